// Round 5
// baseline (169.390 us; speedup 1.0000x reference)
//
#include <hip/hip_runtime.h>
#include <cstdint>

#define Bq 4
#define Lq 4096
#define Hq 256
#define NHq 8
#define Tq 64
#define WINq 16
#define Dq 32
#define NEG_SLOPE 5.0f
#define MASK_FILL -1e12f
#define TLq 64         // l-tile for k_attn
#define MB 32          // rows per block for MFMA GEMMs (512 blocks -> 2/CU)

typedef __attribute__((ext_vector_type(8))) short short8;
typedef __attribute__((ext_vector_type(4))) float f32x4;

__device__ __forceinline__ float leaky(float x) { return x >= 0.f ? x : NEG_SLOPE * x; }

__device__ __forceinline__ uint16_t f2bf(float x) {   // RNE f32->bf16 bits
    uint32_t u = __float_as_uint(x);
    uint32_t r = (u + 0x7fffu + ((u >> 16) & 1u)) >> 16;
    return (uint16_t)r;
}
__device__ __forceinline__ float bf2f(uint16_t h) {
    return __uint_as_float(((uint32_t)h) << 16);
}

// ------- merged prep: blocks 0..127 pack Wc/Wo; blocks 128..383 do types -------
__global__ void k_prep(const float* __restrict__ Wc, const float* __restrict__ Wo,
                       uint16_t* __restrict__ pc_hi, uint16_t* __restrict__ pc_lo,
                       uint16_t* __restrict__ po_hi, uint16_t* __restrict__ po_lo,
                       const float* __restrict__ types, const float* __restrict__ Wt,
                       const float* __restrict__ bt, const float* __restrict__ down,
                       float* __restrict__ types_h, float* __restrict__ types_hT,
                       float* __restrict__ down_t) {
    __shared__ float sin[Hq];
    __shared__ float outr[Hq];
    if (blockIdx.x < 128) {
        int wsel = blockIdx.x >> 6;
        int blk = blockIdx.x & 63;
        const float* W = wsel ? Wo : Wc;
        uint16_t* ph = wsel ? po_hi : pc_hi;
        uint16_t* pl = wsel ? po_lo : pc_lo;
        int base = blk * 1024;
        for (int idx = base + threadIdx.x; idx < base + 1024; idx += 256) {
            int j = idx & 7, l = (idx >> 3) & 63, fragi = idx >> 9;
            int kc = fragi & 7, nt = fragi >> 3;
            int k = kc * 32 + (l >> 4) * 8 + j;
            int c = nt * 16 + (l & 15);
            float x = W[k * Hq + c];
            uint16_t h = f2bf(x);
            ph[idx] = h;
            pl[idx] = f2bf(x - bf2f(h));
        }
        return;
    }
    // ---- types projection + down_t + transposed copy ----
    int row = blockIdx.x - 128;    // b*T + t
    int h = threadIdx.x;
    int b = row >> 6, t = row & 63;
    sin[h] = types[(size_t)row * Hq + h];
    __syncthreads();
    float acc = bt[h];
    for (int k = 0; k < Hq; k += 4) {
        float4 iv = *(const float4*)&sin[k];
        acc = fmaf(iv.x, Wt[(k + 0) * Hq + h], acc);
        acc = fmaf(iv.y, Wt[(k + 1) * Hq + h], acc);
        acc = fmaf(iv.z, Wt[(k + 2) * Hq + h], acc);
        acc = fmaf(iv.w, Wt[(k + 3) * Hq + h], acc);
    }
    types_h[(size_t)row * Hq + h] = acc;
    types_hT[(size_t)(b * Hq + h) * Tq + t] = acc;   // [b][n][d][t]
    outr[h] = acc;
    __syncthreads();
    if (h < NHq) {
        float s = 0.f;
        for (int d = 0; d < Dq; ++d) s += outr[h * Dq + d] * down[h * Dq + d];
        down_t[(b * NHq + h) * Tq + t] = s;
    }
}

// ---------------- context projection via MFMA (bf16 hi/lo split) ----------------
// R14: MB=32 — each wave does 2 row-tiles sharing B-fragments (halves weight
// L2 traffic, halves barriers/row).
#define APAD 264       // bf16 row stride for A tiles
#define OPAD 258       // f32 row stride for output staging
__global__ void __launch_bounds__(256) k_ctx(
        const float* __restrict__ ctx,
        const uint16_t* __restrict__ wp_hi, const uint16_t* __restrict__ wp_lo,
        const float* __restrict__ bc, const float* __restrict__ upon,
        const float* __restrict__ down,
        float* __restrict__ ctx_hT, float* __restrict__ uq,
        float* __restrict__ dsv) {
    int row0 = blockIdx.x * MB;
    int b = row0 >> 12, l0 = row0 & (Lq - 1);
    int tid = threadIdx.x;
    int w = tid >> 6, l = tid & 63;
    __shared__ __align__(16) char smem_raw[MB * APAD * 4];   // 33.8 KB
    uint16_t* a_hi = (uint16_t*)smem_raw;            // [32][APAD]
    uint16_t* a_lo = a_hi + MB * APAD;
    float* outb = (float*)smem_raw;                  // reused: [32][OPAD]

    {   // stage + split 32 rows (2048 float4, 8/thread)
        const float4* src = (const float4*)(ctx + (size_t)row0 * Hq);
#pragma unroll
        for (int j = 0; j < 8; ++j) {
            int f = tid + j * 256;
            int r = f >> 6, cg = f & 63;
            float4 v = src[f];
            uint16_t h0 = f2bf(v.x), h1 = f2bf(v.y), h2 = f2bf(v.z), h3 = f2bf(v.w);
            ushort4 hh = {h0, h1, h2, h3};
            ushort4 ll = {f2bf(v.x - bf2f(h0)), f2bf(v.y - bf2f(h1)),
                          f2bf(v.z - bf2f(h2)), f2bf(v.w - bf2f(h3))};
            *(ushort4*)&a_hi[r * APAD + cg * 4] = hh;
            *(ushort4*)&a_lo[r * APAD + cg * 4] = ll;
        }
    }
    __syncthreads();

    int nt0 = w * 4;
    int m = l & 15, quad = l >> 4;
    f32x4 acc[2][4];
#pragma unroll
    for (int rt = 0; rt < 2; ++rt)
#pragma unroll
        for (int t = 0; t < 4; ++t) acc[rt][t] = (f32x4){0.f, 0.f, 0.f, 0.f};
#pragma unroll
    for (int kc = 0; kc < 8; ++kc) {
        short8 ah0 = *(const short8*)&a_hi[m * APAD + kc * 32 + quad * 8];
        short8 al0 = *(const short8*)&a_lo[m * APAD + kc * 32 + quad * 8];
        short8 ah1 = *(const short8*)&a_hi[(16 + m) * APAD + kc * 32 + quad * 8];
        short8 al1 = *(const short8*)&a_lo[(16 + m) * APAD + kc * 32 + quad * 8];
#pragma unroll
        for (int t = 0; t < 4; ++t) {
            int fragi = (nt0 + t) * 8 + kc;
            short8 wh = *(const short8*)&wp_hi[fragi * 512 + l * 8];
            short8 wl = *(const short8*)&wp_lo[fragi * 512 + l * 8];
            acc[0][t] = __builtin_amdgcn_mfma_f32_16x16x32_bf16(ah0, wh, acc[0][t], 0, 0, 0);
            acc[0][t] = __builtin_amdgcn_mfma_f32_16x16x32_bf16(ah0, wl, acc[0][t], 0, 0, 0);
            acc[0][t] = __builtin_amdgcn_mfma_f32_16x16x32_bf16(al0, wh, acc[0][t], 0, 0, 0);
            acc[1][t] = __builtin_amdgcn_mfma_f32_16x16x32_bf16(ah1, wh, acc[1][t], 0, 0, 0);
            acc[1][t] = __builtin_amdgcn_mfma_f32_16x16x32_bf16(ah1, wl, acc[1][t], 0, 0, 0);
            acc[1][t] = __builtin_amdgcn_mfma_f32_16x16x32_bf16(al1, wh, acc[1][t], 0, 0, 0);
        }
    }
    __syncthreads();

#pragma unroll
    for (int rt = 0; rt < 2; ++rt)
#pragma unroll
    for (int t = 0; t < 4; ++t) {
        int col = (nt0 + t) * 16 + m;
        float bv = bc[col];
#pragma unroll
        for (int r = 0; r < 4; ++r)
            outb[(16 * rt + quad * 4 + r) * OPAD + col] = acc[rt][t][r] + bv;
    }
    __syncthreads();

    {   // uq / dsv: 256 threads -> (r 0..31, n 0..7)
        int r = tid >> 3, n = tid & 7;
        float su = 0.f, sd = 0.f;
        for (int d = 0; d < Dq; ++d) {
            float v = outb[r * OPAD + n * Dq + d];
            su += v * upon[n * Dq + d];
            sd += v * down[n * Dq + d];
        }
        uq[(b * NHq + n) * Lq + l0 + r] = su;
        dsv[(b * NHq + n) * Lq + l0 + r] = sd;
    }
    // transposed store, coalesced: 8 lanes cooperate per channel (128 B rows)
    {
#pragma unroll
        for (int jj = 0; jj < 8; ++jj) {
            int f = tid + jj * 256;
            int ch = f >> 3, part = f & 7;
            float4 o;
            o.x = outb[(4 * part + 0) * OPAD + ch];
            o.y = outb[(4 * part + 1) * OPAD + ch];
            o.z = outb[(4 * part + 2) * OPAD + ch];
            o.w = outb[(4 * part + 3) * OPAD + ch];
            *(float4*)(ctx_hT + (size_t)(b * Hq + ch) * Lq + l0 + 4 * part) = o;
        }
    }
}

// ---------------- attention: tiled (b, n, 64 l's) per block ----------------
// R14: C-write via in-wave LDS transpose -> coalesced 16B uint4 stores (64B
// segments); ctx for the +context add loaded early (hidden under epilogue).
__global__ void __launch_bounds__(256, 3) k_attn(
        const float* __restrict__ ctx_hT, const float* __restrict__ types_h,
        const float* __restrict__ types_hT, const float* __restrict__ cross,
        const float* __restrict__ uq, const float* __restrict__ dsv,
        const float* __restrict__ dt, const unsigned char* __restrict__ maskp,
        const float* __restrict__ ctx,
        uint16_t* __restrict__ updp_hi, uint16_t* __restrict__ updp_lo) {
    int blk = blockIdx.x;
    int lt = blk & 63, n = (blk >> 6) & 7, b = blk >> 9;
    int l0 = lt * TLq;
    int tid = threadIdx.x;
    int g = tid >> 6;          // wave id -> l-group 16g..16g+15
    int lane = tid & 63;
    int Q = lane >> 4, s = lane & 15;
    bool mask_b8 = (maskp[1] != 0);

    __shared__ __align__(16) char smem[53952];
    // region A (pre-B4): TT + chxT; alias (post-B4): waT; alias (tail): cstage
    uint16_t* TT_hi     = (uint16_t*)(smem);            // [64][40]  5120 B
    uint16_t* TT_lo     = (uint16_t*)(smem + 5120);
    uint16_t* chxT_hi   = (uint16_t*)(smem + 10240);    // [80][40]  6400 B
    uint16_t* chxT_lo   = (uint16_t*)(smem + 16640);    //       (ends 23040)
    uint16_t* waT_hi    = (uint16_t*)(smem);            // alias: [64][72] 9216 B
    uint16_t* waT_lo    = (uint16_t*)(smem + 9216);     //       (ends 18432)
    // region B: crle (own-wave rows); alias: waw (same own-wave rows)
    uint16_t* crle_hi   = (uint16_t*)(smem + 23040);    // [64][40]  5120 B
    uint16_t* crle_lo   = (uint16_t*)(smem + 28160);    //       (ends 33280)
    uint16_t* waw_hi    = (uint16_t*)(smem + 23040);    // alias
    uint16_t* waw_lo    = (uint16_t*)(smem + 28160);
    // persistent:
    uint16_t* chvt_hi   = (uint16_t*)(smem + 33280);    // [32][80]  5120 B
    uint16_t* chvt_lo   = (uint16_t*)(smem + 38400);
    uint16_t* ttvt_hi   = (uint16_t*)(smem + 43520);    // [32][72]  4608 B
    uint16_t* ttvt_lo   = (uint16_t*)(smem + 48128);
    float* uqe   = (float*)(smem + 52736);   // [80]
    float* dsve  = (float*)(smem + 53056);   // [80]  base = l0-16
    float* maskf = (float*)(smem + 53376);   // [80]
    float* dts   = (float*)(smem + 53696);   // [64]  (end 53952)

    // ---------------- cross -> registers (L2-cached, no LDS, no barrier) -----
    short8 cb0h, cb0l, cb1h, cb1l;
    {
        const float* cbp = cross + n * (Dq * Dq) + s;
        float c0v[8], c1v[8];
#pragma unroll
        for (int j = 0; j < 8; ++j) {
            c0v[j] = cbp[(8 * Q + j) * 32];
            c1v[j] = cbp[(8 * Q + j) * 32 + 16];
        }
#pragma unroll
        for (int j = 0; j < 8; ++j) {
            uint16_t h0 = f2bf(c0v[j]);
            cb0h[j] = (short)h0; cb0l[j] = (short)f2bf(c0v[j] - bf2f(h0));
            uint16_t h1 = f2bf(c1v[j]);
            cb1h[j] = (short)h1; cb1l[j] = (short)f2bf(c1v[j] - bf2f(h1));
        }
    }

    // ---------------- phase 0: staging ----------------
    {   // window values ctx_h[d][l0..l0+79] -> chvt [d][w] + chxT [w][d]
        int d_ = tid >> 3, k_ = tid & 7, base = k_ * 10;
        const float* grow = ctx_hT + ((size_t)(b * NHq + n) * Dq + d_) * Lq;
        float cv[10];
        if (l0 <= Lq - 80) {
            const float2* g2 = (const float2*)(grow + l0 + base);
#pragma unroll
            for (int j = 0; j < 5; ++j) { float2 v = g2[j]; cv[2*j] = v.x; cv[2*j+1] = v.y; }
        } else {
#pragma unroll
            for (int m = 0; m < 10; ++m) {
                int gl = l0 + base + m;
                cv[m] = grow[gl >= Lq ? gl - Lq : gl];
            }
        }
        uint16_t hh[10], ll[10];
#pragma unroll
        for (int m = 0; m < 10; ++m) {
            hh[m] = f2bf(cv[m]);
            ll[m] = f2bf(cv[m] - bf2f(hh[m]));
        }
#pragma unroll
        for (int j = 0; j < 5; ++j) {
            *(uint*)&chvt_hi[d_ * 80 + base + 2*j] = (uint)hh[2*j] | ((uint)hh[2*j+1] << 16);
            *(uint*)&chvt_lo[d_ * 80 + base + 2*j] = (uint)ll[2*j] | ((uint)ll[2*j+1] << 16);
        }
#pragma unroll
        for (int m = 0; m < 10; ++m) {
            chxT_hi[(base + m) * 40 + d_] = hh[m];
            chxT_lo[(base + m) * 40 + d_] = ll[m];
        }
    }
    {   // TT [t][e]
        int t = tid >> 2, c8 = (tid & 3) * 8;
        const float* src = types_h + (size_t)(b * Tq + t) * Hq + n * Dq + c8;
        float4 v0 = *(const float4*)src, v1 = *(const float4*)(src + 4);
        float vv[8] = {v0.x, v0.y, v0.z, v0.w, v1.x, v1.y, v1.z, v1.w};
        uint hp[4], lp[4];
#pragma unroll
        for (int j = 0; j < 4; ++j) {
            uint16_t h0 = f2bf(vv[2*j]), h1 = f2bf(vv[2*j+1]);
            hp[j] = (uint)h0 | ((uint)h1 << 16);
            lp[j] = (uint)f2bf(vv[2*j] - bf2f(h0)) | ((uint)f2bf(vv[2*j+1] - bf2f(h1)) << 16);
        }
        *(uint4*)&TT_hi[t * 40 + c8] = make_uint4(hp[0], hp[1], hp[2], hp[3]);
        *(uint4*)&TT_lo[t * 40 + c8] = make_uint4(lp[0], lp[1], lp[2], lp[3]);
    }
    {   // TTVT [d][t]
        int d_ = tid >> 3, t8 = (tid & 7) * 8;
        const float* src = types_hT + ((size_t)(b * Hq) + n * Dq + d_) * Tq + t8;
        float4 v0 = *(const float4*)src, v1 = *(const float4*)(src + 4);
        float vv[8] = {v0.x, v0.y, v0.z, v0.w, v1.x, v1.y, v1.z, v1.w};
        uint hp[4], lp[4];
#pragma unroll
        for (int j = 0; j < 4; ++j) {
            uint16_t h0 = f2bf(vv[2*j]), h1 = f2bf(vv[2*j+1]);
            hp[j] = (uint)h0 | ((uint)h1 << 16);
            lp[j] = (uint)f2bf(vv[2*j] - bf2f(h0)) | ((uint)f2bf(vv[2*j+1] - bf2f(h1)) << 16);
        }
        *(uint4*)&ttvt_hi[d_ * 72 + t8] = make_uint4(hp[0], hp[1], hp[2], hp[3]);
        *(uint4*)&ttvt_lo[d_ * 72 + t8] = make_uint4(lp[0], lp[1], lp[2], lp[3]);
    }
    if (tid < 80) {
        int gl = l0 + tid;
        int glw = gl >= Lq ? gl - Lq : gl;
        uqe[tid] = uq[(b * NHq + n) * Lq + glw];
        unsigned char mb = mask_b8 ? maskp[b * Lq + glw]
                                   : maskp[(size_t)(b * Lq + glw) * 4];
        maskf[tid] = mb ? 1.f : 0.f;
    } else if (tid >= 96 && tid < 176) {
        int i = tid - 96;
        int gl = l0 - 16 + i;
        int glw = gl < 0 ? gl + Lq : (gl >= Lq ? gl - Lq : gl);
        dsve[i] = dsv[(b * NHq + n) * Lq + glw];
    } else if (tid >= 192) {
        dts[tid - 192] = dt[(b * NHq + n) * Tq + (tid - 192)];
    }
    __syncthreads();    // B1

    // ---------------- P1: cr[l][e] = ctx_h[l] . cross ----------------
    f32x4 cr0 = (f32x4){0.f, 0.f, 0.f, 0.f};
    f32x4 cr1 = (f32x4){0.f, 0.f, 0.f, 0.f};
    {
        short8 axh = *(const short8*)&chxT_hi[(16*g + s) * 40 + 8*Q];
        short8 axl = *(const short8*)&chxT_lo[(16*g + s) * 40 + 8*Q];
        cr0 = __builtin_amdgcn_mfma_f32_16x16x32_bf16(axh, cb0h, cr0, 0, 0, 0);
        cr0 = __builtin_amdgcn_mfma_f32_16x16x32_bf16(axl, cb0h, cr0, 0, 0, 0);
        cr0 = __builtin_amdgcn_mfma_f32_16x16x32_bf16(axh, cb0l, cr0, 0, 0, 0);
        cr1 = __builtin_amdgcn_mfma_f32_16x16x32_bf16(axh, cb1h, cr1, 0, 0, 0);
        cr1 = __builtin_amdgcn_mfma_f32_16x16x32_bf16(axl, cb1h, cr1, 0, 0, 0);
        cr1 = __builtin_amdgcn_mfma_f32_16x16x32_bf16(axh, cb1l, cr1, 0, 0, 0);
    }

    // crle [l][e] bf16 hi/lo (own-wave rows; dedicated region -> no barrier)
#pragma unroll
    for (int r = 0; r < 4; ++r) {
        int row = 16*g + 4*Q + r;
        uint16_t h0 = f2bf(cr0[r]);
        crle_hi[row * 40 + s] = h0;
        crle_lo[row * 40 + s] = f2bf(cr0[r] - bf2f(h0));
        uint16_t h1 = f2bf(cr1[r]);
        crle_hi[row * 40 + 16 + s] = h1;
        crle_lo[row * 40 + 16 + s] = f2bf(cr1[r] - bf2f(h1));
    }

    // ---------------- P2 (t-scores) + P3 (window dots) ----------------
    f32x4 p2[4], p3[2];
#pragma unroll
    for (int c = 0; c < 4; ++c) p2[c] = (f32x4){0.f, 0.f, 0.f, 0.f};
#pragma unroll
    for (int t_ = 0; t_ < 2; ++t_) p3[t_] = (f32x4){0.f, 0.f, 0.f, 0.f};
    {
        short8 cah = *(const short8*)&crle_hi[(16*g + s) * 40 + 8*Q];
        short8 cal = *(const short8*)&crle_lo[(16*g + s) * 40 + 8*Q];
#pragma unroll
        for (int c = 0; c < 4; ++c) {
            short8 bh = *(const short8*)&TT_hi[(s + 16*c) * 40 + 8*Q];
            short8 bl = *(const short8*)&TT_lo[(s + 16*c) * 40 + 8*Q];
            p2[c] = __builtin_amdgcn_mfma_f32_16x16x32_bf16(cah, bh, p2[c], 0, 0, 0);
            p2[c] = __builtin_amdgcn_mfma_f32_16x16x32_bf16(cal, bh, p2[c], 0, 0, 0);
            p2[c] = __builtin_amdgcn_mfma_f32_16x16x32_bf16(cah, bl, p2[c], 0, 0, 0);
        }
#pragma unroll
        for (int t_ = 0; t_ < 2; ++t_) {
            short8 bh = *(const short8*)&chxT_hi[(16*g + 16*t_ + s) * 40 + 8*Q];
            short8 bl = *(const short8*)&chxT_lo[(16*g + 16*t_ + s) * 40 + 8*Q];
            p3[t_] = __builtin_amdgcn_mfma_f32_16x16x32_bf16(cah, bh, p3[t_], 0, 0, 0);
            p3[t_] = __builtin_amdgcn_mfma_f32_16x16x32_bf16(cal, bh, p3[t_], 0, 0, 0);
            p3[t_] = __builtin_amdgcn_mfma_f32_16x16x32_bf16(cah, bl, p3[t_], 0, 0, 0);
        }
    }

    // ---------------- softmax (C-layout: lane = col, 4 rows) ----------------
    float uqr[4], cmr[4], dsr[4], dd[4];
    *(float4*)uqr = *(const float4*)&uqe[16*g + 4*Q];
    *(float4*)cmr = *(const float4*)&maskf[16*g + 4*Q];
    *(float4*)dsr = *(const float4*)&dsve[16*g + 4*Q + 16];
#pragma unroll
    for (int r = 0; r < 4; ++r) dd[r] = dsve[16*g + 4*Q + s + r];
    float dtv[4], uw[2], mw[2];
#pragma unroll
    for (int c = 0; c < 4; ++c) dtv[c] = dts[s + 16*c];
#pragma unroll
    for (int t_ = 0; t_ < 2; ++t_) {
        uw[t_] = uqe[16*g + s + 16*t_];
        mw[t_] = maskf[16*g + s + 16*t_];
    }
    float dsb[4];
#pragma unroll
    for (int r = 0; r < 4; ++r) dsb[r] = __shfl(p3[0][r], 20*Q + r);

    float stt[4][4], rup[2][4], rdn[4], rdn16[4];
#pragma unroll
    for (int c = 0; c < 4; ++c)
#pragma unroll
        for (int r = 0; r < 4; ++r)
            stt[c][r] = leaky(uqr[r] + dtv[c] + p2[c][r]);
#pragma unroll
    for (int t_ = 0; t_ < 2; ++t_)
#pragma unroll
        for (int r = 0; r < 4; ++r) {
            int u = s + 16*t_ - 4*Q - r;
            bool ok = (u >= 1) && (u <= 16) && (l0 + 16*g + s + 16*t_ < Lq)
                      && (mw[t_] > 0.5f);
            rup[t_][r] = ok ? leaky(uw[t_] + dsr[r] + p3[t_][r]) : MASK_FILL;
        }
#pragma unroll
    for (int r = 0; r < 4; ++r) {
        bool okd = (l0 + 16*g + 4*Q + r + s >= 16) && (cmr[r] > 0.5f);
        rdn[r]   = okd ? leaky(uqr[r] + dd[r] + dsb[r]) : MASK_FILL;
        rdn16[r] = (s == 0 && cmr[r] > 0.5f) ? leaky(uqr[r] + dsr[r] + dsb[r])
                                             : MASK_FILL;
    }

    float mx[4];
#pragma unroll
    for (int r = 0; r < 4; ++r) {
        float m = fmaxf(fmaxf(stt[0][r], stt[1][r]), fmaxf(stt[2][r], stt[3][r]));
        m = fmaxf(m, fmaxf(rup[0][r], rup[1][r]));
        m = fmaxf(m, fmaxf(rdn[r], rdn16[r]));
        mx[r] = m;
    }
#pragma unroll
    for (int msk = 1; msk <= 8; msk <<= 1)
#pragma unroll
        for (int r = 0; r < 4; ++r) mx[r] = fmaxf(mx[r], __shfl_xor(mx[r], msk));

    float sTU[4] = {0.f, 0.f, 0.f, 0.f}, sD[4];
#pragma unroll
    for (int c = 0; c < 4; ++c)
#pragma unroll
        for (int r = 0; r < 4; ++r) {
            stt[c][r] = __expf(stt[c][r] - mx[r]);
            sTU[r] += stt[c][r];
        }
#pragma unroll
    for (int t_ = 0; t_ < 2; ++t_)
#pragma unroll
        for (int r = 0; r < 4; ++r) {
            rup[t_][r] = __expf(rup[t_][r] - mx[r]);
            sTU[r] += rup[t_][r];
        }
#pragma unroll
    for (int r = 0; r < 4; ++r) {
        rdn[r] = __expf(rdn[r] - mx[r]);
        rdn16[r] = __expf(rdn16[r] - mx[r]);
        sD[r] = rdn[r] + rdn16[r];
    }
#pragma unroll
    for (int msk = 1; msk <= 8; msk <<= 1)
#pragma unroll
        for (int r = 0; r < 4; ++r) {
            sTU[r] += __shfl_xor(sTU[r], msk);
            sD[r]  += __shfl_xor(sD[r], msk);
        }
    float inv[4], wself[4];
#pragma unroll
    for (int r = 0; r < 4; ++r) {
        inv[r] = 1.f / (sTU[r] + sD[r]);
        wself[r] = sD[r] * inv[r];
    }

    __syncthreads();    // B4: all TT/chxT reads done; alias as waT/waw

    // ---------------- weight writes (bf16 hi/lo) ----------------
#pragma unroll
    for (int r = 0; r < 4; ++r) {
        int row = 16*g + 4*Q + r;
#pragma unroll
        for (int c = 0; c < 4; ++c) {
            float v = stt[c][r] * inv[r];
            uint16_t h = f2bf(v);
            waT_hi[row * 72 + s + 16*c] = h;
            waT_lo[row * 72 + s + 16*c] = f2bf(v - bf2f(h));
        }
#pragma unroll
        for (int t_ = 0; t_ < 2; ++t_) {
            int u = s + 16*t_ - 4*Q - r;
            float v = (u == 0) ? wself[r]
                    : ((u >= 1 && u <= 16) ? rup[t_][r] * inv[r] : 0.f);
            uint16_t h = f2bf(v);
            waw_hi[row * 40 + s + 16*t_] = h;
            waw_lo[row * 40 + s + 16*t_] = f2bf(v - bf2f(h));
        }
    }
    // (no barrier: epilogue reads only rows this wave wrote)

    // early ctx load for the +context add ([l][d] orientation, coalesced);
    // ~36 MFMAs below hide the latency
    int rowl = lane & 15, p = lane >> 4;
    int lcol = l0 + 16*g + rowl;
    float4 cx0, cx1;
    {
        const float4* cp = (const float4*)(ctx + (size_t)(b * Lq + lcol) * Hq
                                           + n * Dq + 8*p);
        cx0 = cp[0]; cx1 = cp[1];
    }

    // ---------------- epilogue MFMAs: updT[d][l] ----------------
    f32x4 a0 = (f32x4){0.f, 0.f, 0.f, 0.f};
    f32x4 a1 = (f32x4){0.f, 0.f, 0.f, 0.f};
#pragma unroll
    for (int ks = 0; ks < 2; ++ks) {
        short8 bh = *(const short8*)&waT_hi[(16*g + s) * 72 + 32*ks + 8*Q];
        short8 bl = *(const short8*)&waT_lo[(16*g + s) * 72 + 32*ks + 8*Q];
        short8 t0h = *(const short8*)&ttvt_hi[s * 72 + 32*ks + 8*Q];
        short8 t0l = *(const short8*)&ttvt_lo[s * 72 + 32*ks + 8*Q];
        short8 t1h = *(const short8*)&ttvt_hi[(16 + s) * 72 + 32*ks + 8*Q];
        short8 t1l = *(const short8*)&ttvt_lo[(16 + s) * 72 + 32*ks + 8*Q];
        a0 = __builtin_amdgcn_mfma_f32_16x16x32_bf16(t0h, bh, a0, 0, 0, 0);
        a0 = __builtin_amdgcn_mfma_f32_16x16x32_bf16(t0l, bh, a0, 0, 0, 0);
        a0 = __builtin_amdgcn_mfma_f32_16x16x32_bf16(t0h, bl, a0, 0, 0, 0);
        a1 = __builtin_amdgcn_mfma_f32_16x16x32_bf16(t1h, bh, a1, 0, 0, 0);
        a1 = __builtin_amdgcn_mfma_f32_16x16x32_bf16(t1l, bh, a1, 0, 0, 0);
        a1 = __builtin_amdgcn_mfma_f32_16x16x32_bf16(t1h, bl, a1, 0, 0, 0);
    }
    {
        short8 wbh = *(const short8*)&waw_hi[(16*g + s) * 40 + 8*Q];
        short8 wbl = *(const short8*)&waw_lo[(16*g + s) * 40 + 8*Q];
        short8 c0h = *(const short8*)&chvt_hi[s * 80 + 16*g + 8*Q];
        short8 c0l = *(const short8*)&chvt_lo[s * 80 + 16*g + 8*Q];
        short8 c1h = *(const short8*)&chvt_hi[(16 + s) * 80 + 16*g + 8*Q];
        short8 c1l = *(const short8*)&chvt_lo[(16 + s) * 80 + 16*g + 8*Q];
        a0 = __builtin_amdgcn_mfma_f32_16x16x32_bf16(c0h, wbh, a0, 0, 0, 0);
        a0 = __builtin_amdgcn_mfma_f32_16x16x32_bf16(c0l, wbh, a0, 0, 0, 0);
        a0 = __builtin_amdgcn_mfma_f32_16x16x32_bf16(c0h, wbl, a0, 0, 0, 0);
        a1 = __builtin_amdgcn_mfma_f32_16x16x32_bf16(c1h, wbh, a1, 0, 0, 0);
        a1 = __builtin_amdgcn_mfma_f32_16x16x32_bf16(c1l, wbh, a1, 0, 0, 0);
        a1 = __builtin_amdgcn_mfma_f32_16x16x32_bf16(c1h, wbl, a1, 0, 0, 0);
    }

    // ---------- C write: in-wave LDS transpose -> coalesced stores ----------
    // stage [l][d] f32 into this wave's waT rows (2304 B/wave), rotate-swizzle
    // by 4*l within the 32-dword row to avoid bank camping. In-wave DS ops are
    // processed in order -> no barrier (own-wave rows only).
    {
        float* cst = (float*)(smem + 2304 * g);
        *(float4*)&cst[s * 32 + ((4*Q + 4*s) & 31)]
            = make_float4(a0[0], a0[1], a0[2], a0[3]);
        *(float4*)&cst[s * 32 + ((16 + 4*Q + 4*s) & 31)]
            = make_float4(a1[0], a1[1], a1[2], a1[3]);
        float4 u0 = *(float4*)&cst[rowl * 32 + ((8*p + 4*rowl) & 31)];
        float4 u1 = *(float4*)&cst[rowl * 32 + ((8*p + 4 + 4*rowl) & 31)];
        float vv[8] = {u0.x + cx0.x, u0.y + cx0.y, u0.z + cx0.z, u0.w + cx0.w,
                       u1.x + cx1.x, u1.y + cx1.y, u1.z + cx1.z, u1.w + cx1.w};
        uint hu[4], lu[4];
#pragma unroll
        for (int j = 0; j < 4; ++j) {
            uint16_t h0 = f2bf(vv[2*j]), h1 = f2bf(vv[2*j+1]);
            hu[j] = (uint)h0 | ((uint)h1 << 16);
            lu[j] = (uint)f2bf(vv[2*j] - bf2f(h0))
                  | ((uint)f2bf(vv[2*j+1] - bf2f(h1)) << 16);
        }
        size_t obase = (size_t)(b * Lq + lcol) * Hq + n * Dq + 8*p;
        *(uint4*)(updp_hi + obase) = make_uint4(hu[0], hu[1], hu[2], hu[3]);
        *(uint4*)(updp_lo + obase) = make_uint4(lu[0], lu[1], lu[2], lu[3]);
    }
}

// ------- output GEMM via MFMA + tanh (LDS-free, barrier-free, MB=32) --------
__global__ void __launch_bounds__(256) k_out(
        const uint16_t* __restrict__ up_hi, const uint16_t* __restrict__ up_lo,
        const uint16_t* __restrict__ wp_hi, const uint16_t* __restrict__ wp_lo,
        const float* __restrict__ bo, float* __restrict__ out) {
    int row0 = blockIdx.x * MB;
    int tid = threadIdx.x;
    int w = tid >> 6, l = tid & 63;
    int nt0 = w * 4;
    int m = l & 15, quad = l >> 4;
    const uint16_t* ah_base0 = up_hi + (size_t)(row0 + m) * Hq + quad * 8;
    const uint16_t* al_base0 = up_lo + (size_t)(row0 + m) * Hq + quad * 8;
    const uint16_t* ah_base1 = ah_base0 + 16 * Hq;
    const uint16_t* al_base1 = al_base0 + 16 * Hq;

    f32x4 acc[2][4];
#pragma unroll
    for (int rt = 0; rt < 2; ++rt)
#pragma unroll
        for (int t = 0; t < 4; ++t) acc[rt][t] = (f32x4){0.f, 0.f, 0.f, 0.f};
#pragma unroll
    for (int kc = 0; kc < 8; ++kc) {
        short8 ah0 = *(const short8*)(ah_base0 + kc * 32);
        short8 al0 = *(const short8*)(al_base0 + kc * 32);
        short8 ah1 = *(const short8*)(ah_base1 + kc * 32);
        short8 al1 = *(const short8*)(al_base1 + kc * 32);
#pragma unroll
        for (int t = 0; t < 4; ++t) {
            int fragi = (nt0 + t) * 8 + kc;
            short8 wh = *(const short8*)&wp_hi[fragi * 512 + l * 8];
            short8 wl = *(const short8*)&wp_lo[fragi * 512 + l * 8];
            acc[0][t] = __builtin_amdgcn_mfma_f32_16x16x32_bf16(ah0, wh, acc[0][t], 0, 0, 0);
            acc[0][t] = __builtin_amdgcn_mfma_f32_16x16x32_bf16(ah0, wl, acc[0][t], 0, 0, 0);
            acc[0][t] = __builtin_amdgcn_mfma_f32_16x16x32_bf16(al0, wh, acc[0][t], 0, 0, 0);
            acc[1][t] = __builtin_amdgcn_mfma_f32_16x16x32_bf16(ah1, wh, acc[1][t], 0, 0, 0);
            acc[1][t] = __builtin_amdgcn_mfma_f32_16x16x32_bf16(ah1, wl, acc[1][t], 0, 0, 0);
            acc[1][t] = __builtin_amdgcn_mfma_f32_16x16x32_bf16(al1, wh, acc[1][t], 0, 0, 0);
        }
    }
#pragma unroll
    for (int rt = 0; rt < 2; ++rt)
#pragma unroll
    for (int t = 0; t < 4; ++t) {
        int col = (nt0 + t) * 16 + m;
        float bv = bo[col];
#pragma unroll
        for (int r = 0; r < 4; ++r)
            out[(size_t)(row0 + 16 * rt + quad * 4 + r) * Hq + col]
                = tanhf(acc[rt][t][r] + bv);
    }
}

extern "C" void kernel_launch(void* const* d_in, const int* in_sizes, int n_in,
                              void* d_out, int out_size, void* d_ws, size_t ws_size,
                              hipStream_t stream) {
    const float* context   = (const float*)d_in[0];
    const float* types     = (const float*)d_in[1];
    const unsigned char* cmask = (const unsigned char*)d_in[2];
    const float* W_types   = (const float*)d_in[3];
    const float* b_types   = (const float*)d_in[4];
    const float* W_context = (const float*)d_in[5];
    const float* b_context = (const float*)d_in[6];
    const float* upon      = (const float*)d_in[7];
    const float* down      = (const float*)d_in[8];
    const float* cross     = (const float*)d_in[9];
    const float* W_out     = (const float*)d_in[10];
    const float* b_out     = (const float*)d_in[11];
    float* out = (float*)d_out;
    float* ws  = (float*)d_ws;

    float* ctx_hT     = ws;                            // [b][n][d][l] 16 MB
    uint16_t* updp_hi = (uint16_t*)(ws + 4194304);     // 8 MB packed hi
    uint16_t* updp_lo = updp_hi + 4194304;             // 8 MB packed lo
    uint16_t* wcp_hi  = (uint16_t*)(ws + 8388608);
    uint16_t* wcp_lo  = wcp_hi + 65536;
    uint16_t* wop_hi  = wcp_hi + 131072;
    uint16_t* wop_lo  = wcp_hi + 196608;

    float* types_h  = out;            // 65536   [b][t][h]
    float* types_hT = out + 65536;    // 65536   [b][n][d][t]
    float* down_t   = out + 131072;   // 2048
    float* uqp      = out + 133120;   // 131072
    float* dsvp     = out + 264192;   // 131072

    k_prep<<<128 + Bq * Tq, 256, 0, stream>>>(W_context, W_out,
                                              wcp_hi, wcp_lo, wop_hi, wop_lo,
                                              types, W_types, b_types, down,
                                              types_h, types_hT, down_t);
    k_ctx<<<Bq * Lq / MB, 256, 0, stream>>>(context, wcp_hi, wcp_lo, b_context,
                                            upon, down, ctx_hT, uqp, dsvp);
    k_attn<<<Bq * NHq * (Lq / TLq), 256, 0, stream>>>(ctx_hT, types_h, types_hT, cross,
                                                      uqp, dsvp, down_t, cmask,
                                                      context, updp_hi, updp_lo);
    k_out<<<Bq * Lq / MB, 256, 0, stream>>>(updp_hi, updp_lo, wop_hi, wop_lo,
                                            b_out, out);
}

// Round 6
// 164.129 us; speedup vs baseline: 1.0320x; 1.0320x over previous
//
#include <hip/hip_runtime.h>
#include <cstdint>

#define Bq 4
#define Lq 4096
#define Hq 256
#define NHq 8
#define Tq 64
#define WINq 16
#define Dq 32
#define NEG_SLOPE 5.0f
#define MASK_FILL -1e12f
#define TLq 64         // l-tile for k_attn
#define MB 16          // rows per block for MFMA GEMMs (1024 blocks -> 4/CU)

typedef __attribute__((ext_vector_type(8))) short short8;
typedef __attribute__((ext_vector_type(4))) float f32x4;

__device__ __forceinline__ float leaky(float x) { return x >= 0.f ? x : NEG_SLOPE * x; }

__device__ __forceinline__ uint16_t f2bf(float x) {   // RNE f32->bf16 bits
    uint32_t u = __float_as_uint(x);
    uint32_t r = (u + 0x7fffu + ((u >> 16) & 1u)) >> 16;
    return (uint16_t)r;
}
__device__ __forceinline__ float bf2f(uint16_t h) {
    return __uint_as_float(((uint32_t)h) << 16);
}

// ------- merged prep: blocks 0..127 pack Wc/Wo; blocks 128..383 do types -------
__global__ void k_prep(const float* __restrict__ Wc, const float* __restrict__ Wo,
                       uint16_t* __restrict__ pc_hi, uint16_t* __restrict__ pc_lo,
                       uint16_t* __restrict__ po_hi, uint16_t* __restrict__ po_lo,
                       const float* __restrict__ types, const float* __restrict__ Wt,
                       const float* __restrict__ bt, const float* __restrict__ down,
                       float* __restrict__ types_h, float* __restrict__ types_hT,
                       float* __restrict__ down_t) {
    __shared__ float sin[Hq];
    __shared__ float outr[Hq];
    if (blockIdx.x < 128) {
        int wsel = blockIdx.x >> 6;
        int blk = blockIdx.x & 63;
        const float* W = wsel ? Wo : Wc;
        uint16_t* ph = wsel ? po_hi : pc_hi;
        uint16_t* pl = wsel ? po_lo : pc_lo;
        int base = blk * 1024;
        for (int idx = base + threadIdx.x; idx < base + 1024; idx += 256) {
            int j = idx & 7, l = (idx >> 3) & 63, fragi = idx >> 9;
            int kc = fragi & 7, nt = fragi >> 3;
            int k = kc * 32 + (l >> 4) * 8 + j;
            int c = nt * 16 + (l & 15);
            float x = W[k * Hq + c];
            uint16_t h = f2bf(x);
            ph[idx] = h;
            pl[idx] = f2bf(x - bf2f(h));
        }
        return;
    }
    // ---- types projection + down_t + transposed copy ----
    int row = blockIdx.x - 128;    // b*T + t
    int h = threadIdx.x;
    int b = row >> 6, t = row & 63;
    sin[h] = types[(size_t)row * Hq + h];
    __syncthreads();
    float acc = bt[h];
    for (int k = 0; k < Hq; k += 4) {
        float4 iv = *(const float4*)&sin[k];
        acc = fmaf(iv.x, Wt[(k + 0) * Hq + h], acc);
        acc = fmaf(iv.y, Wt[(k + 1) * Hq + h], acc);
        acc = fmaf(iv.z, Wt[(k + 2) * Hq + h], acc);
        acc = fmaf(iv.w, Wt[(k + 3) * Hq + h], acc);
    }
    types_h[(size_t)row * Hq + h] = acc;
    types_hT[(size_t)(b * Hq + h) * Tq + t] = acc;   // [b][n][d][t]
    outr[h] = acc;
    __syncthreads();
    if (h < NHq) {
        float s = 0.f;
        for (int d = 0; d < Dq; ++d) s += outr[h * Dq + d] * down[h * Dq + d];
        down_t[(b * NHq + h) * Tq + t] = s;
    }
}

// ---------------- context projection via MFMA (bf16 hi/lo split) ----------------
#define APAD 264       // bf16 row stride for A tiles
#define OPAD 258       // f32 row stride for output staging
__global__ void __launch_bounds__(256) k_ctx(
        const float* __restrict__ ctx,
        const uint16_t* __restrict__ wp_hi, const uint16_t* __restrict__ wp_lo,
        const float* __restrict__ bc, const float* __restrict__ upon,
        const float* __restrict__ down,
        float* __restrict__ ctx_hT, float* __restrict__ uq,
        float* __restrict__ dsv) {
    int row0 = blockIdx.x * MB;
    int b = row0 >> 12, l0 = row0 & (Lq - 1);
    int tid = threadIdx.x;
    int w = tid >> 6, l = tid & 63;
    __shared__ __align__(16) char smem_raw[MB * APAD * 4];   // 16.9 KB
    uint16_t* a_hi = (uint16_t*)smem_raw;            // [16][APAD]
    uint16_t* a_lo = a_hi + MB * APAD;
    float* outb = (float*)smem_raw;                  // reused: [16][OPAD]

    {
        const float4* src = (const float4*)(ctx + (size_t)row0 * Hq);
#pragma unroll
        for (int j = 0; j < 4; ++j) {
            int f = tid + j * 256;
            int r = f >> 6, cg = f & 63;
            float4 v = src[f];
            uint16_t h0 = f2bf(v.x), h1 = f2bf(v.y), h2 = f2bf(v.z), h3 = f2bf(v.w);
            ushort4 hh = {h0, h1, h2, h3};
            ushort4 ll = {f2bf(v.x - bf2f(h0)), f2bf(v.y - bf2f(h1)),
                          f2bf(v.z - bf2f(h2)), f2bf(v.w - bf2f(h3))};
            *(ushort4*)&a_hi[r * APAD + cg * 4] = hh;
            *(ushort4*)&a_lo[r * APAD + cg * 4] = ll;
        }
    }
    __syncthreads();

    int nt0 = w * 4;
    int m = l & 15, quad = l >> 4;
    f32x4 acc[4];
#pragma unroll
    for (int t = 0; t < 4; ++t) acc[t] = (f32x4){0.f, 0.f, 0.f, 0.f};
#pragma unroll
    for (int kc = 0; kc < 8; ++kc) {
        short8 ah = *(const short8*)&a_hi[m * APAD + kc * 32 + quad * 8];
        short8 al = *(const short8*)&a_lo[m * APAD + kc * 32 + quad * 8];
#pragma unroll
        for (int t = 0; t < 4; ++t) {
            int fragi = (nt0 + t) * 8 + kc;
            short8 wh = *(const short8*)&wp_hi[fragi * 512 + l * 8];
            short8 wl = *(const short8*)&wp_lo[fragi * 512 + l * 8];
            acc[t] = __builtin_amdgcn_mfma_f32_16x16x32_bf16(ah, wh, acc[t], 0, 0, 0);
            acc[t] = __builtin_amdgcn_mfma_f32_16x16x32_bf16(ah, wl, acc[t], 0, 0, 0);
            acc[t] = __builtin_amdgcn_mfma_f32_16x16x32_bf16(al, wh, acc[t], 0, 0, 0);
        }
    }
    __syncthreads();

#pragma unroll
    for (int t = 0; t < 4; ++t) {
        int col = (nt0 + t) * 16 + m;
        float bv = bc[col];
#pragma unroll
        for (int r = 0; r < 4; ++r)
            outb[(quad * 4 + r) * OPAD + col] = acc[t][r] + bv;
    }
    __syncthreads();

    if (tid < MB * NHq) {
        int r = tid >> 3, n = tid & 7;
        float su = 0.f, sd = 0.f;
        for (int d = 0; d < Dq; ++d) {
            float v = outb[r * OPAD + n * Dq + d];
            su += v * upon[n * Dq + d];
            sd += v * down[n * Dq + d];
        }
        uq[(b * NHq + n) * Lq + l0 + r] = su;
        dsv[(b * NHq + n) * Lq + l0 + r] = sd;
    }
    // transposed store, coalesced: 4 lanes cooperate per channel -> 64B segments
    {
#pragma unroll
        for (int jj = 0; jj < 4; ++jj) {
            int f = tid + jj * 256;
            int ch = f >> 2, part = f & 3;
            float4 o;
            o.x = outb[(4 * part + 0) * OPAD + ch];
            o.y = outb[(4 * part + 1) * OPAD + ch];
            o.z = outb[(4 * part + 2) * OPAD + ch];
            o.w = outb[(4 * part + 3) * OPAD + ch];
            *(float4*)(ctx_hT + (size_t)(b * Hq + ch) * Lq + l0 + 4 * part) = o;
        }
    }
}

// ---------------- attention: tiled (b, n, 64 l's) per block ----------------
// (unchanged from R14)
__global__ void __launch_bounds__(256, 3) k_attn(
        const float* __restrict__ ctx_hT, const float* __restrict__ types_h,
        const float* __restrict__ types_hT, const float* __restrict__ cross,
        const float* __restrict__ uq, const float* __restrict__ dsv,
        const float* __restrict__ dt, const unsigned char* __restrict__ maskp,
        const float* __restrict__ ctx,
        uint16_t* __restrict__ updp_hi, uint16_t* __restrict__ updp_lo) {
    int blk = blockIdx.x;
    int lt = blk & 63, n = (blk >> 6) & 7, b = blk >> 9;
    int l0 = lt * TLq;
    int tid = threadIdx.x;
    int g = tid >> 6;          // wave id -> l-group 16g..16g+15
    int lane = tid & 63;
    int Q = lane >> 4, s = lane & 15;
    bool mask_b8 = (maskp[1] != 0);

    __shared__ __align__(16) char smem[53952];
    uint16_t* TT_hi     = (uint16_t*)(smem);            // [64][40]  5120 B
    uint16_t* TT_lo     = (uint16_t*)(smem + 5120);
    uint16_t* chxT_hi   = (uint16_t*)(smem + 10240);    // [80][40]  6400 B
    uint16_t* chxT_lo   = (uint16_t*)(smem + 16640);    //       (ends 23040)
    uint16_t* waT_hi    = (uint16_t*)(smem);            // alias: [64][72] 9216 B
    uint16_t* waT_lo    = (uint16_t*)(smem + 9216);     //       (ends 18432)
    uint16_t* crle_hi   = (uint16_t*)(smem + 23040);    // [64][40]  5120 B
    uint16_t* crle_lo   = (uint16_t*)(smem + 28160);    //       (ends 33280)
    uint16_t* waw_hi    = (uint16_t*)(smem + 23040);    // alias
    uint16_t* waw_lo    = (uint16_t*)(smem + 28160);
    uint16_t* chvt_hi   = (uint16_t*)(smem + 33280);    // [32][80]  5120 B
    uint16_t* chvt_lo   = (uint16_t*)(smem + 38400);
    uint16_t* ttvt_hi   = (uint16_t*)(smem + 43520);    // [32][72]  4608 B
    uint16_t* ttvt_lo   = (uint16_t*)(smem + 48128);
    float* uqe   = (float*)(smem + 52736);   // [80]
    float* dsve  = (float*)(smem + 53056);   // [80]  base = l0-16
    float* maskf = (float*)(smem + 53376);   // [80]
    float* dts   = (float*)(smem + 53696);   // [64]  (end 53952)

    // ---------------- cross -> registers (L2-cached, no LDS, no barrier) -----
    short8 cb0h, cb0l, cb1h, cb1l;
    {
        const float* cbp = cross + n * (Dq * Dq) + s;
        float c0v[8], c1v[8];
#pragma unroll
        for (int j = 0; j < 8; ++j) {
            c0v[j] = cbp[(8 * Q + j) * 32];
            c1v[j] = cbp[(8 * Q + j) * 32 + 16];
        }
#pragma unroll
        for (int j = 0; j < 8; ++j) {
            uint16_t h0 = f2bf(c0v[j]);
            cb0h[j] = (short)h0; cb0l[j] = (short)f2bf(c0v[j] - bf2f(h0));
            uint16_t h1 = f2bf(c1v[j]);
            cb1h[j] = (short)h1; cb1l[j] = (short)f2bf(c1v[j] - bf2f(h1));
        }
    }

    // ---------------- phase 0: staging ----------------
    {   // window values ctx_h[d][l0..l0+79] -> chvt [d][w] + chxT [w][d]
        int d_ = tid >> 3, k_ = tid & 7, base = k_ * 10;
        const float* grow = ctx_hT + ((size_t)(b * NHq + n) * Dq + d_) * Lq;
        float cv[10];
        if (l0 <= Lq - 80) {
            const float2* g2 = (const float2*)(grow + l0 + base);
#pragma unroll
            for (int j = 0; j < 5; ++j) { float2 v = g2[j]; cv[2*j] = v.x; cv[2*j+1] = v.y; }
        } else {
#pragma unroll
            for (int m = 0; m < 10; ++m) {
                int gl = l0 + base + m;
                cv[m] = grow[gl >= Lq ? gl - Lq : gl];
            }
        }
        uint16_t hh[10], ll[10];
#pragma unroll
        for (int m = 0; m < 10; ++m) {
            hh[m] = f2bf(cv[m]);
            ll[m] = f2bf(cv[m] - bf2f(hh[m]));
        }
#pragma unroll
        for (int j = 0; j < 5; ++j) {
            *(uint*)&chvt_hi[d_ * 80 + base + 2*j] = (uint)hh[2*j] | ((uint)hh[2*j+1] << 16);
            *(uint*)&chvt_lo[d_ * 80 + base + 2*j] = (uint)ll[2*j] | ((uint)ll[2*j+1] << 16);
        }
#pragma unroll
        for (int m = 0; m < 10; ++m) {
            chxT_hi[(base + m) * 40 + d_] = hh[m];
            chxT_lo[(base + m) * 40 + d_] = ll[m];
        }
    }
    {   // TT [t][e]
        int t = tid >> 2, c8 = (tid & 3) * 8;
        const float* src = types_h + (size_t)(b * Tq + t) * Hq + n * Dq + c8;
        float4 v0 = *(const float4*)src, v1 = *(const float4*)(src + 4);
        float vv[8] = {v0.x, v0.y, v0.z, v0.w, v1.x, v1.y, v1.z, v1.w};
        uint hp[4], lp[4];
#pragma unroll
        for (int j = 0; j < 4; ++j) {
            uint16_t h0 = f2bf(vv[2*j]), h1 = f2bf(vv[2*j+1]);
            hp[j] = (uint)h0 | ((uint)h1 << 16);
            lp[j] = (uint)f2bf(vv[2*j] - bf2f(h0)) | ((uint)f2bf(vv[2*j+1] - bf2f(h1)) << 16);
        }
        *(uint4*)&TT_hi[t * 40 + c8] = make_uint4(hp[0], hp[1], hp[2], hp[3]);
        *(uint4*)&TT_lo[t * 40 + c8] = make_uint4(lp[0], lp[1], lp[2], lp[3]);
    }
    {   // TTVT [d][t]
        int d_ = tid >> 3, t8 = (tid & 7) * 8;
        const float* src = types_hT + ((size_t)(b * Hq) + n * Dq + d_) * Tq + t8;
        float4 v0 = *(const float4*)src, v1 = *(const float4*)(src + 4);
        float vv[8] = {v0.x, v0.y, v0.z, v0.w, v1.x, v1.y, v1.z, v1.w};
        uint hp[4], lp[4];
#pragma unroll
        for (int j = 0; j < 4; ++j) {
            uint16_t h0 = f2bf(vv[2*j]), h1 = f2bf(vv[2*j+1]);
            hp[j] = (uint)h0 | ((uint)h1 << 16);
            lp[j] = (uint)f2bf(vv[2*j] - bf2f(h0)) | ((uint)f2bf(vv[2*j+1] - bf2f(h1)) << 16);
        }
        *(uint4*)&ttvt_hi[d_ * 72 + t8] = make_uint4(hp[0], hp[1], hp[2], hp[3]);
        *(uint4*)&ttvt_lo[d_ * 72 + t8] = make_uint4(lp[0], lp[1], lp[2], lp[3]);
    }
    if (tid < 80) {
        int gl = l0 + tid;
        int glw = gl >= Lq ? gl - Lq : gl;
        uqe[tid] = uq[(b * NHq + n) * Lq + glw];
        unsigned char mb = mask_b8 ? maskp[b * Lq + glw]
                                   : maskp[(size_t)(b * Lq + glw) * 4];
        maskf[tid] = mb ? 1.f : 0.f;
    } else if (tid >= 96 && tid < 176) {
        int i = tid - 96;
        int gl = l0 - 16 + i;
        int glw = gl < 0 ? gl + Lq : (gl >= Lq ? gl - Lq : gl);
        dsve[i] = dsv[(b * NHq + n) * Lq + glw];
    } else if (tid >= 192) {
        dts[tid - 192] = dt[(b * NHq + n) * Tq + (tid - 192)];
    }
    __syncthreads();    // B1

    // ---------------- P1: cr[l][e] = ctx_h[l] . cross ----------------
    f32x4 cr0 = (f32x4){0.f, 0.f, 0.f, 0.f};
    f32x4 cr1 = (f32x4){0.f, 0.f, 0.f, 0.f};
    {
        short8 axh = *(const short8*)&chxT_hi[(16*g + s) * 40 + 8*Q];
        short8 axl = *(const short8*)&chxT_lo[(16*g + s) * 40 + 8*Q];
        cr0 = __builtin_amdgcn_mfma_f32_16x16x32_bf16(axh, cb0h, cr0, 0, 0, 0);
        cr0 = __builtin_amdgcn_mfma_f32_16x16x32_bf16(axl, cb0h, cr0, 0, 0, 0);
        cr0 = __builtin_amdgcn_mfma_f32_16x16x32_bf16(axh, cb0l, cr0, 0, 0, 0);
        cr1 = __builtin_amdgcn_mfma_f32_16x16x32_bf16(axh, cb1h, cr1, 0, 0, 0);
        cr1 = __builtin_amdgcn_mfma_f32_16x16x32_bf16(axl, cb1h, cr1, 0, 0, 0);
        cr1 = __builtin_amdgcn_mfma_f32_16x16x32_bf16(axh, cb1l, cr1, 0, 0, 0);
    }

    // crle [l][e] bf16 hi/lo (own-wave rows; dedicated region -> no barrier)
#pragma unroll
    for (int r = 0; r < 4; ++r) {
        int row = 16*g + 4*Q + r;
        uint16_t h0 = f2bf(cr0[r]);
        crle_hi[row * 40 + s] = h0;
        crle_lo[row * 40 + s] = f2bf(cr0[r] - bf2f(h0));
        uint16_t h1 = f2bf(cr1[r]);
        crle_hi[row * 40 + 16 + s] = h1;
        crle_lo[row * 40 + 16 + s] = f2bf(cr1[r] - bf2f(h1));
    }

    // ---------------- P2 (t-scores) + P3 (window dots) ----------------
    f32x4 p2[4], p3[2];
#pragma unroll
    for (int c = 0; c < 4; ++c) p2[c] = (f32x4){0.f, 0.f, 0.f, 0.f};
#pragma unroll
    for (int t_ = 0; t_ < 2; ++t_) p3[t_] = (f32x4){0.f, 0.f, 0.f, 0.f};
    {
        short8 cah = *(const short8*)&crle_hi[(16*g + s) * 40 + 8*Q];
        short8 cal = *(const short8*)&crle_lo[(16*g + s) * 40 + 8*Q];
#pragma unroll
        for (int c = 0; c < 4; ++c) {
            short8 bh = *(const short8*)&TT_hi[(s + 16*c) * 40 + 8*Q];
            short8 bl = *(const short8*)&TT_lo[(s + 16*c) * 40 + 8*Q];
            p2[c] = __builtin_amdgcn_mfma_f32_16x16x32_bf16(cah, bh, p2[c], 0, 0, 0);
            p2[c] = __builtin_amdgcn_mfma_f32_16x16x32_bf16(cal, bh, p2[c], 0, 0, 0);
            p2[c] = __builtin_amdgcn_mfma_f32_16x16x32_bf16(cah, bl, p2[c], 0, 0, 0);
        }
#pragma unroll
        for (int t_ = 0; t_ < 2; ++t_) {
            short8 bh = *(const short8*)&chxT_hi[(16*g + 16*t_ + s) * 40 + 8*Q];
            short8 bl = *(const short8*)&chxT_lo[(16*g + 16*t_ + s) * 40 + 8*Q];
            p3[t_] = __builtin_amdgcn_mfma_f32_16x16x32_bf16(cah, bh, p3[t_], 0, 0, 0);
            p3[t_] = __builtin_amdgcn_mfma_f32_16x16x32_bf16(cal, bh, p3[t_], 0, 0, 0);
            p3[t_] = __builtin_amdgcn_mfma_f32_16x16x32_bf16(cah, bl, p3[t_], 0, 0, 0);
        }
    }

    // ---------------- softmax (C-layout: lane = col, 4 rows) ----------------
    float uqr[4], cmr[4], dsr[4], dd[4];
    *(float4*)uqr = *(const float4*)&uqe[16*g + 4*Q];
    *(float4*)cmr = *(const float4*)&maskf[16*g + 4*Q];
    *(float4*)dsr = *(const float4*)&dsve[16*g + 4*Q + 16];
#pragma unroll
    for (int r = 0; r < 4; ++r) dd[r] = dsve[16*g + 4*Q + s + r];
    float dtv[4], uw[2], mw[2];
#pragma unroll
    for (int c = 0; c < 4; ++c) dtv[c] = dts[s + 16*c];
#pragma unroll
    for (int t_ = 0; t_ < 2; ++t_) {
        uw[t_] = uqe[16*g + s + 16*t_];
        mw[t_] = maskf[16*g + s + 16*t_];
    }
    float dsb[4];
#pragma unroll
    for (int r = 0; r < 4; ++r) dsb[r] = __shfl(p3[0][r], 20*Q + r);

    float stt[4][4], rup[2][4], rdn[4], rdn16[4];
#pragma unroll
    for (int c = 0; c < 4; ++c)
#pragma unroll
        for (int r = 0; r < 4; ++r)
            stt[c][r] = leaky(uqr[r] + dtv[c] + p2[c][r]);
#pragma unroll
    for (int t_ = 0; t_ < 2; ++t_)
#pragma unroll
        for (int r = 0; r < 4; ++r) {
            int u = s + 16*t_ - 4*Q - r;
            bool ok = (u >= 1) && (u <= 16) && (l0 + 16*g + s + 16*t_ < Lq)
                      && (mw[t_] > 0.5f);
            rup[t_][r] = ok ? leaky(uw[t_] + dsr[r] + p3[t_][r]) : MASK_FILL;
        }
#pragma unroll
    for (int r = 0; r < 4; ++r) {
        bool okd = (l0 + 16*g + 4*Q + r + s >= 16) && (cmr[r] > 0.5f);
        rdn[r]   = okd ? leaky(uqr[r] + dd[r] + dsb[r]) : MASK_FILL;
        rdn16[r] = (s == 0 && cmr[r] > 0.5f) ? leaky(uqr[r] + dsr[r] + dsb[r])
                                             : MASK_FILL;
    }

    float mx[4];
#pragma unroll
    for (int r = 0; r < 4; ++r) {
        float m = fmaxf(fmaxf(stt[0][r], stt[1][r]), fmaxf(stt[2][r], stt[3][r]));
        m = fmaxf(m, fmaxf(rup[0][r], rup[1][r]));
        m = fmaxf(m, fmaxf(rdn[r], rdn16[r]));
        mx[r] = m;
    }
#pragma unroll
    for (int msk = 1; msk <= 8; msk <<= 1)
#pragma unroll
        for (int r = 0; r < 4; ++r) mx[r] = fmaxf(mx[r], __shfl_xor(mx[r], msk));

    float sTU[4] = {0.f, 0.f, 0.f, 0.f}, sD[4];
#pragma unroll
    for (int c = 0; c < 4; ++c)
#pragma unroll
        for (int r = 0; r < 4; ++r) {
            stt[c][r] = __expf(stt[c][r] - mx[r]);
            sTU[r] += stt[c][r];
        }
#pragma unroll
    for (int t_ = 0; t_ < 2; ++t_)
#pragma unroll
        for (int r = 0; r < 4; ++r) {
            rup[t_][r] = __expf(rup[t_][r] - mx[r]);
            sTU[r] += rup[t_][r];
        }
#pragma unroll
    for (int r = 0; r < 4; ++r) {
        rdn[r] = __expf(rdn[r] - mx[r]);
        rdn16[r] = __expf(rdn16[r] - mx[r]);
        sD[r] = rdn[r] + rdn16[r];
    }
#pragma unroll
    for (int msk = 1; msk <= 8; msk <<= 1)
#pragma unroll
        for (int r = 0; r < 4; ++r) {
            sTU[r] += __shfl_xor(sTU[r], msk);
            sD[r]  += __shfl_xor(sD[r], msk);
        }
    float inv[4], wself[4];
#pragma unroll
    for (int r = 0; r < 4; ++r) {
        inv[r] = 1.f / (sTU[r] + sD[r]);
        wself[r] = sD[r] * inv[r];
    }

    __syncthreads();    // B4: all TT/chxT reads done; alias as waT/waw

    // ---------------- weight writes (bf16 hi/lo) ----------------
#pragma unroll
    for (int r = 0; r < 4; ++r) {
        int row = 16*g + 4*Q + r;
#pragma unroll
        for (int c = 0; c < 4; ++c) {
            float v = stt[c][r] * inv[r];
            uint16_t h = f2bf(v);
            waT_hi[row * 72 + s + 16*c] = h;
            waT_lo[row * 72 + s + 16*c] = f2bf(v - bf2f(h));
        }
#pragma unroll
        for (int t_ = 0; t_ < 2; ++t_) {
            int u = s + 16*t_ - 4*Q - r;
            float v = (u == 0) ? wself[r]
                    : ((u >= 1 && u <= 16) ? rup[t_][r] * inv[r] : 0.f);
            uint16_t h = f2bf(v);
            waw_hi[row * 40 + s + 16*t_] = h;
            waw_lo[row * 40 + s + 16*t_] = f2bf(v - bf2f(h));
        }
    }
    // (no barrier: epilogue reads only rows this wave wrote)

    // early ctx load for the +context add ([l][d] orientation, coalesced)
    int rowl = lane & 15, p = lane >> 4;
    int lcol = l0 + 16*g + rowl;
    float4 cx0, cx1;
    {
        const float4* cp = (const float4*)(ctx + (size_t)(b * Lq + lcol) * Hq
                                           + n * Dq + 8*p);
        cx0 = cp[0]; cx1 = cp[1];
    }

    // ---------------- epilogue MFMAs: updT[d][l] ----------------
    f32x4 a0 = (f32x4){0.f, 0.f, 0.f, 0.f};
    f32x4 a1 = (f32x4){0.f, 0.f, 0.f, 0.f};
#pragma unroll
    for (int ks = 0; ks < 2; ++ks) {
        short8 bh = *(const short8*)&waT_hi[(16*g + s) * 72 + 32*ks + 8*Q];
        short8 bl = *(const short8*)&waT_lo[(16*g + s) * 72 + 32*ks + 8*Q];
        short8 t0h = *(const short8*)&ttvt_hi[s * 72 + 32*ks + 8*Q];
        short8 t0l = *(const short8*)&ttvt_lo[s * 72 + 32*ks + 8*Q];
        short8 t1h = *(const short8*)&ttvt_hi[(16 + s) * 72 + 32*ks + 8*Q];
        short8 t1l = *(const short8*)&ttvt_lo[(16 + s) * 72 + 32*ks + 8*Q];
        a0 = __builtin_amdgcn_mfma_f32_16x16x32_bf16(t0h, bh, a0, 0, 0, 0);
        a0 = __builtin_amdgcn_mfma_f32_16x16x32_bf16(t0l, bh, a0, 0, 0, 0);
        a0 = __builtin_amdgcn_mfma_f32_16x16x32_bf16(t0h, bl, a0, 0, 0, 0);
        a1 = __builtin_amdgcn_mfma_f32_16x16x32_bf16(t1h, bh, a1, 0, 0, 0);
        a1 = __builtin_amdgcn_mfma_f32_16x16x32_bf16(t1l, bh, a1, 0, 0, 0);
        a1 = __builtin_amdgcn_mfma_f32_16x16x32_bf16(t1h, bl, a1, 0, 0, 0);
    }
    {
        short8 wbh = *(const short8*)&waw_hi[(16*g + s) * 40 + 8*Q];
        short8 wbl = *(const short8*)&waw_lo[(16*g + s) * 40 + 8*Q];
        short8 c0h = *(const short8*)&chvt_hi[s * 80 + 16*g + 8*Q];
        short8 c0l = *(const short8*)&chvt_lo[s * 80 + 16*g + 8*Q];
        short8 c1h = *(const short8*)&chvt_hi[(16 + s) * 80 + 16*g + 8*Q];
        short8 c1l = *(const short8*)&chvt_lo[(16 + s) * 80 + 16*g + 8*Q];
        a0 = __builtin_amdgcn_mfma_f32_16x16x32_bf16(c0h, wbh, a0, 0, 0, 0);
        a0 = __builtin_amdgcn_mfma_f32_16x16x32_bf16(c0l, wbh, a0, 0, 0, 0);
        a0 = __builtin_amdgcn_mfma_f32_16x16x32_bf16(c0h, wbl, a0, 0, 0, 0);
        a1 = __builtin_amdgcn_mfma_f32_16x16x32_bf16(c1h, wbh, a1, 0, 0, 0);
        a1 = __builtin_amdgcn_mfma_f32_16x16x32_bf16(c1l, wbh, a1, 0, 0, 0);
        a1 = __builtin_amdgcn_mfma_f32_16x16x32_bf16(c1h, wbl, a1, 0, 0, 0);
    }

    // ---------- C write: in-wave LDS transpose -> coalesced stores ----------
    {
        float* cst = (float*)(smem + 2304 * g);
        *(float4*)&cst[s * 32 + ((4*Q + 4*s) & 31)]
            = make_float4(a0[0], a0[1], a0[2], a0[3]);
        *(float4*)&cst[s * 32 + ((16 + 4*Q + 4*s) & 31)]
            = make_float4(a1[0], a1[1], a1[2], a1[3]);
        float4 u0 = *(float4*)&cst[rowl * 32 + ((8*p + 4*rowl) & 31)];
        float4 u1 = *(float4*)&cst[rowl * 32 + ((8*p + 4 + 4*rowl) & 31)];
        float vv[8] = {u0.x + cx0.x, u0.y + cx0.y, u0.z + cx0.z, u0.w + cx0.w,
                       u1.x + cx1.x, u1.y + cx1.y, u1.z + cx1.z, u1.w + cx1.w};
        uint hu[4], lu[4];
#pragma unroll
        for (int j = 0; j < 4; ++j) {
            uint16_t h0 = f2bf(vv[2*j]), h1 = f2bf(vv[2*j+1]);
            hu[j] = (uint)h0 | ((uint)h1 << 16);
            lu[j] = (uint)f2bf(vv[2*j] - bf2f(h0))
                  | ((uint)f2bf(vv[2*j+1] - bf2f(h1)) << 16);
        }
        size_t obase = (size_t)(b * Lq + lcol) * Hq + n * Dq + 8*p;
        *(uint4*)(updp_hi + obase) = make_uint4(hu[0], hu[1], hu[2], hu[3]);
        *(uint4*)(updp_lo + obase) = make_uint4(lu[0], lu[1], lu[2], lu[3]);
    }
}

// ------ output GEMM via MFMA + tanh (LDS-staged packed A, coalesced) --------
__global__ void __launch_bounds__(256) k_out(
        const uint16_t* __restrict__ up_hi, const uint16_t* __restrict__ up_lo,
        const uint16_t* __restrict__ wp_hi, const uint16_t* __restrict__ wp_lo,
        const float* __restrict__ bo, float* __restrict__ out) {
    int row0 = blockIdx.x * MB;
    int tid = threadIdx.x;
    int w = tid >> 6, l = tid & 63;
    __shared__ __align__(16) uint16_t a_hi[MB * APAD];
    __shared__ __align__(16) uint16_t a_lo[MB * APAD];

    {   // coalesced copy of pre-packed A: 16 rows x 256 cols x 2 buffers
        const uint4* sh = (const uint4*)(up_hi + (size_t)row0 * Hq);
        const uint4* sl = (const uint4*)(up_lo + (size_t)row0 * Hq);
#pragma unroll
        for (int j = 0; j < 2; ++j) {
            int f = tid + j * 256;
            int r = f >> 5, c8 = (f & 31) * 8;
            *(uint4*)&a_hi[r * APAD + c8] = sh[f];
            *(uint4*)&a_lo[r * APAD + c8] = sl[f];
        }
    }
    __syncthreads();

    int nt0 = w * 4;
    int m = l & 15, quad = l >> 4;
    f32x4 acc[4];
#pragma unroll
    for (int t = 0; t < 4; ++t) acc[t] = (f32x4){0.f, 0.f, 0.f, 0.f};
#pragma unroll
    for (int kc = 0; kc < 8; ++kc) {
        short8 ah = *(const short8*)&a_hi[m * APAD + kc * 32 + quad * 8];
        short8 al = *(const short8*)&a_lo[m * APAD + kc * 32 + quad * 8];
#pragma unroll
        for (int t = 0; t < 4; ++t) {
            int fragi = (nt0 + t) * 8 + kc;
            short8 wh = *(const short8*)&wp_hi[fragi * 512 + l * 8];
            short8 wl = *(const short8*)&wp_lo[fragi * 512 + l * 8];
            acc[t] = __builtin_amdgcn_mfma_f32_16x16x32_bf16(ah, wh, acc[t], 0, 0, 0);
            acc[t] = __builtin_amdgcn_mfma_f32_16x16x32_bf16(ah, wl, acc[t], 0, 0, 0);
            acc[t] = __builtin_amdgcn_mfma_f32_16x16x32_bf16(al, wh, acc[t], 0, 0, 0);
        }
    }
#pragma unroll
    for (int t = 0; t < 4; ++t) {
        int col = (nt0 + t) * 16 + m;
        float bv = bo[col];
#pragma unroll
        for (int r = 0; r < 4; ++r)
            out[(size_t)(row0 + quad * 4 + r) * Hq + col] = tanhf(acc[t][r] + bv);
    }
}

extern "C" void kernel_launch(void* const* d_in, const int* in_sizes, int n_in,
                              void* d_out, int out_size, void* d_ws, size_t ws_size,
                              hipStream_t stream) {
    const float* context   = (const float*)d_in[0];
    const float* types     = (const float*)d_in[1];
    const unsigned char* cmask = (const unsigned char*)d_in[2];
    const float* W_types   = (const float*)d_in[3];
    const float* b_types   = (const float*)d_in[4];
    const float* W_context = (const float*)d_in[5];
    const float* b_context = (const float*)d_in[6];
    const float* upon      = (const float*)d_in[7];
    const float* down      = (const float*)d_in[8];
    const float* cross     = (const float*)d_in[9];
    const float* W_out     = (const float*)d_in[10];
    const float* b_out     = (const float*)d_in[11];
    float* out = (float*)d_out;
    float* ws  = (float*)d_ws;

    float* ctx_hT     = ws;                            // [b][n][d][l] 16 MB
    uint16_t* updp_hi = (uint16_t*)(ws + 4194304);     // 8 MB packed hi
    uint16_t* updp_lo = updp_hi + 4194304;             // 8 MB packed lo
    uint16_t* wcp_hi  = (uint16_t*)(ws + 8388608);
    uint16_t* wcp_lo  = wcp_hi + 65536;
    uint16_t* wop_hi  = wcp_hi + 131072;
    uint16_t* wop_lo  = wcp_hi + 196608;

    float* types_h  = out;            // 65536   [b][t][h]
    float* types_hT = out + 65536;    // 65536   [b][n][d][t]
    float* down_t   = out + 131072;   // 2048
    float* uqp      = out + 133120;   // 131072
    float* dsvp     = out + 264192;   // 131072

    k_prep<<<128 + Bq * Tq, 256, 0, stream>>>(W_context, W_out,
                                              wcp_hi, wcp_lo, wop_hi, wop_lo,
                                              types, W_types, b_types, down,
                                              types_h, types_hT, down_t);
    k_ctx<<<Bq * Lq / MB, 256, 0, stream>>>(context, wcp_hi, wcp_lo, b_context,
                                            upon, down, ctx_hT, uqp, dsvp);
    k_attn<<<Bq * NHq * (Lq / TLq), 256, 0, stream>>>(ctx_hT, types_h, types_hT, cross,
                                                      uqp, dsvp, down_t, cmask,
                                                      context, updp_hi, updp_lo);
    k_out<<<Bq * Lq / MB, 256, 0, stream>>>(updp_hi, updp_lo, wop_hi, wop_lo,
                                            b_out, out);
}

// Round 7
// 162.985 us; speedup vs baseline: 1.0393x; 1.0070x over previous
//
#include <hip/hip_runtime.h>
#include <cstdint>

#define Bq 4
#define Lq 4096
#define Hq 256
#define NHq 8
#define Tq 64
#define WINq 16
#define Dq 32
#define NEG_SLOPE 5.0f
#define MASK_FILL -1e12f
#define TLq 64         // l-tile for k_attn
#define MB 16          // rows per block for MFMA GEMMs (1024 blocks -> 4/CU)

typedef __attribute__((ext_vector_type(8))) short short8;
typedef __attribute__((ext_vector_type(4))) float f32x4;

__device__ __forceinline__ float leaky(float x) { return x >= 0.f ? x : NEG_SLOPE * x; }

__device__ __forceinline__ uint16_t f2bf(float x) {   // RNE f32->bf16 bits
    uint32_t u = __float_as_uint(x);
    uint32_t r = (u + 0x7fffu + ((u >> 16) & 1u)) >> 16;
    return (uint16_t)r;
}
__device__ __forceinline__ float bf2f(uint16_t h) {
    return __uint_as_float(((uint32_t)h) << 16);
}

// ------- merged prep: blocks 0..127 pack Wc/Wo; blocks 128..383 do types -------
__global__ void k_prep(const float* __restrict__ Wc, const float* __restrict__ Wo,
                       uint16_t* __restrict__ pc_hi, uint16_t* __restrict__ pc_lo,
                       uint16_t* __restrict__ po_hi, uint16_t* __restrict__ po_lo,
                       const float* __restrict__ types, const float* __restrict__ Wt,
                       const float* __restrict__ bt, const float* __restrict__ down,
                       float* __restrict__ types_h, float* __restrict__ types_hT,
                       float* __restrict__ down_t) {
    __shared__ float sin[Hq];
    __shared__ float outr[Hq];
    if (blockIdx.x < 128) {
        int wsel = blockIdx.x >> 6;
        int blk = blockIdx.x & 63;
        const float* W = wsel ? Wo : Wc;
        uint16_t* ph = wsel ? po_hi : pc_hi;
        uint16_t* pl = wsel ? po_lo : pc_lo;
        int base = blk * 1024;
        for (int idx = base + threadIdx.x; idx < base + 1024; idx += 256) {
            int j = idx & 7, l = (idx >> 3) & 63, fragi = idx >> 9;
            int kc = fragi & 7, nt = fragi >> 3;
            int k = kc * 32 + (l >> 4) * 8 + j;
            int c = nt * 16 + (l & 15);
            float x = W[k * Hq + c];
            uint16_t h = f2bf(x);
            ph[idx] = h;
            pl[idx] = f2bf(x - bf2f(h));
        }
        return;
    }
    // ---- types projection + down_t + transposed copy ----
    int row = blockIdx.x - 128;    // b*T + t
    int h = threadIdx.x;
    int b = row >> 6, t = row & 63;
    sin[h] = types[(size_t)row * Hq + h];
    __syncthreads();
    float acc = bt[h];
    for (int k = 0; k < Hq; k += 4) {
        float4 iv = *(const float4*)&sin[k];
        acc = fmaf(iv.x, Wt[(k + 0) * Hq + h], acc);
        acc = fmaf(iv.y, Wt[(k + 1) * Hq + h], acc);
        acc = fmaf(iv.z, Wt[(k + 2) * Hq + h], acc);
        acc = fmaf(iv.w, Wt[(k + 3) * Hq + h], acc);
    }
    types_h[(size_t)row * Hq + h] = acc;
    types_hT[(size_t)(b * Hq + h) * Tq + t] = acc;   // [b][n][d][t]
    outr[h] = acc;
    __syncthreads();
    if (h < NHq) {
        float s = 0.f;
        for (int d = 0; d < Dq; ++d) s += outr[h * Dq + d] * down[h * Dq + d];
        down_t[(b * NHq + h) * Tq + t] = s;
    }
}

// ---------------- context projection via MFMA (bf16 hi/lo split) ----------------
#define APAD 264       // bf16 row stride for A tiles
#define OPAD 258       // f32 row stride for output staging
__global__ void __launch_bounds__(256) k_ctx(
        const float* __restrict__ ctx,
        const uint16_t* __restrict__ wp_hi, const uint16_t* __restrict__ wp_lo,
        const float* __restrict__ bc, const float* __restrict__ upon,
        const float* __restrict__ down,
        float* __restrict__ ctx_hT, float* __restrict__ uq,
        float* __restrict__ dsv) {
    int row0 = blockIdx.x * MB;
    int b = row0 >> 12, l0 = row0 & (Lq - 1);
    int tid = threadIdx.x;
    int w = tid >> 6, l = tid & 63;
    __shared__ __align__(16) char smem_raw[MB * APAD * 4];   // 16.9 KB
    uint16_t* a_hi = (uint16_t*)smem_raw;            // [16][APAD]
    uint16_t* a_lo = a_hi + MB * APAD;
    float* outb = (float*)smem_raw;                  // reused: [16][OPAD]

    {
        const float4* src = (const float4*)(ctx + (size_t)row0 * Hq);
#pragma unroll
        for (int j = 0; j < 4; ++j) {
            int f = tid + j * 256;
            int r = f >> 6, cg = f & 63;
            float4 v = src[f];
            uint16_t h0 = f2bf(v.x), h1 = f2bf(v.y), h2 = f2bf(v.z), h3 = f2bf(v.w);
            ushort4 hh = {h0, h1, h2, h3};
            ushort4 ll = {f2bf(v.x - bf2f(h0)), f2bf(v.y - bf2f(h1)),
                          f2bf(v.z - bf2f(h2)), f2bf(v.w - bf2f(h3))};
            *(ushort4*)&a_hi[r * APAD + cg * 4] = hh;
            *(ushort4*)&a_lo[r * APAD + cg * 4] = ll;
        }
    }
    __syncthreads();

    int nt0 = w * 4;
    int m = l & 15, quad = l >> 4;
    f32x4 acc[4];
#pragma unroll
    for (int t = 0; t < 4; ++t) acc[t] = (f32x4){0.f, 0.f, 0.f, 0.f};
#pragma unroll
    for (int kc = 0; kc < 8; ++kc) {
        short8 ah = *(const short8*)&a_hi[m * APAD + kc * 32 + quad * 8];
        short8 al = *(const short8*)&a_lo[m * APAD + kc * 32 + quad * 8];
#pragma unroll
        for (int t = 0; t < 4; ++t) {
            int fragi = (nt0 + t) * 8 + kc;
            short8 wh = *(const short8*)&wp_hi[fragi * 512 + l * 8];
            short8 wl = *(const short8*)&wp_lo[fragi * 512 + l * 8];
            acc[t] = __builtin_amdgcn_mfma_f32_16x16x32_bf16(ah, wh, acc[t], 0, 0, 0);
            acc[t] = __builtin_amdgcn_mfma_f32_16x16x32_bf16(ah, wl, acc[t], 0, 0, 0);
            acc[t] = __builtin_amdgcn_mfma_f32_16x16x32_bf16(al, wh, acc[t], 0, 0, 0);
        }
    }
    __syncthreads();

#pragma unroll
    for (int t = 0; t < 4; ++t) {
        int col = (nt0 + t) * 16 + m;
        float bv = bc[col];
#pragma unroll
        for (int r = 0; r < 4; ++r)
            outb[(quad * 4 + r) * OPAD + col] = acc[t][r] + bv;
    }
    __syncthreads();

    if (tid < MB * NHq) {
        int r = tid >> 3, n = tid & 7;
        float su = 0.f, sd = 0.f;
        for (int d = 0; d < Dq; ++d) {
            float v = outb[r * OPAD + n * Dq + d];
            su += v * upon[n * Dq + d];
            sd += v * down[n * Dq + d];
        }
        uq[(b * NHq + n) * Lq + l0 + r] = su;
        dsv[(b * NHq + n) * Lq + l0 + r] = sd;
    }
    // transposed store, coalesced: 4 lanes cooperate per channel -> 64B segments
    {
#pragma unroll
        for (int jj = 0; jj < 4; ++jj) {
            int f = tid + jj * 256;
            int ch = f >> 2, part = f & 3;
            float4 o;
            o.x = outb[(4 * part + 0) * OPAD + ch];
            o.y = outb[(4 * part + 1) * OPAD + ch];
            o.z = outb[(4 * part + 2) * OPAD + ch];
            o.w = outb[(4 * part + 3) * OPAD + ch];
            *(float4*)(ctx_hT + (size_t)(b * Hq + ch) * Lq + l0 + 4 * part) = o;
        }
    }
}

// ---------------- attention: tiled (b, n, 64 l's) per block ----------------
// R16: s_setprio around MFMA clusters; scratch moved to ws (launcher change).
__global__ void __launch_bounds__(256, 3) k_attn(
        const float* __restrict__ ctx_hT, const float* __restrict__ types_h,
        const float* __restrict__ types_hT, const float* __restrict__ cross,
        const float* __restrict__ uq, const float* __restrict__ dsv,
        const float* __restrict__ dt, const unsigned char* __restrict__ maskp,
        const float* __restrict__ ctx,
        uint16_t* __restrict__ updp_hi, uint16_t* __restrict__ updp_lo) {
    int blk = blockIdx.x;
    int lt = blk & 63, n = (blk >> 6) & 7, b = blk >> 9;
    int l0 = lt * TLq;
    int tid = threadIdx.x;
    int g = tid >> 6;          // wave id -> l-group 16g..16g+15
    int lane = tid & 63;
    int Q = lane >> 4, s = lane & 15;
    bool mask_b8 = (maskp[1] != 0);

    __shared__ __align__(16) char smem[53952];
    uint16_t* TT_hi     = (uint16_t*)(smem);            // [64][40]  5120 B
    uint16_t* TT_lo     = (uint16_t*)(smem + 5120);
    uint16_t* chxT_hi   = (uint16_t*)(smem + 10240);    // [80][40]  6400 B
    uint16_t* chxT_lo   = (uint16_t*)(smem + 16640);    //       (ends 23040)
    uint16_t* waT_hi    = (uint16_t*)(smem);            // alias: [64][72] 9216 B
    uint16_t* waT_lo    = (uint16_t*)(smem + 9216);     //       (ends 18432)
    uint16_t* crle_hi   = (uint16_t*)(smem + 23040);    // [64][40]  5120 B
    uint16_t* crle_lo   = (uint16_t*)(smem + 28160);    //       (ends 33280)
    uint16_t* waw_hi    = (uint16_t*)(smem + 23040);    // alias
    uint16_t* waw_lo    = (uint16_t*)(smem + 28160);
    uint16_t* chvt_hi   = (uint16_t*)(smem + 33280);    // [32][80]  5120 B
    uint16_t* chvt_lo   = (uint16_t*)(smem + 38400);
    uint16_t* ttvt_hi   = (uint16_t*)(smem + 43520);    // [32][72]  4608 B
    uint16_t* ttvt_lo   = (uint16_t*)(smem + 48128);
    float* uqe   = (float*)(smem + 52736);   // [80]
    float* dsve  = (float*)(smem + 53056);   // [80]  base = l0-16
    float* maskf = (float*)(smem + 53376);   // [80]
    float* dts   = (float*)(smem + 53696);   // [64]  (end 53952)

    // ---------------- cross -> registers (L2-cached, no LDS, no barrier) -----
    short8 cb0h, cb0l, cb1h, cb1l;
    {
        const float* cbp = cross + n * (Dq * Dq) + s;
        float c0v[8], c1v[8];
#pragma unroll
        for (int j = 0; j < 8; ++j) {
            c0v[j] = cbp[(8 * Q + j) * 32];
            c1v[j] = cbp[(8 * Q + j) * 32 + 16];
        }
#pragma unroll
        for (int j = 0; j < 8; ++j) {
            uint16_t h0 = f2bf(c0v[j]);
            cb0h[j] = (short)h0; cb0l[j] = (short)f2bf(c0v[j] - bf2f(h0));
            uint16_t h1 = f2bf(c1v[j]);
            cb1h[j] = (short)h1; cb1l[j] = (short)f2bf(c1v[j] - bf2f(h1));
        }
    }

    // ---------------- phase 0: staging ----------------
    {   // window values ctx_h[d][l0..l0+79] -> chvt [d][w] + chxT [w][d]
        int d_ = tid >> 3, k_ = tid & 7, base = k_ * 10;
        const float* grow = ctx_hT + ((size_t)(b * NHq + n) * Dq + d_) * Lq;
        float cv[10];
        if (l0 <= Lq - 80) {
            const float2* g2 = (const float2*)(grow + l0 + base);
#pragma unroll
            for (int j = 0; j < 5; ++j) { float2 v = g2[j]; cv[2*j] = v.x; cv[2*j+1] = v.y; }
        } else {
#pragma unroll
            for (int m = 0; m < 10; ++m) {
                int gl = l0 + base + m;
                cv[m] = grow[gl >= Lq ? gl - Lq : gl];
            }
        }
        uint16_t hh[10], ll[10];
#pragma unroll
        for (int m = 0; m < 10; ++m) {
            hh[m] = f2bf(cv[m]);
            ll[m] = f2bf(cv[m] - bf2f(hh[m]));
        }
#pragma unroll
        for (int j = 0; j < 5; ++j) {
            *(uint*)&chvt_hi[d_ * 80 + base + 2*j] = (uint)hh[2*j] | ((uint)hh[2*j+1] << 16);
            *(uint*)&chvt_lo[d_ * 80 + base + 2*j] = (uint)ll[2*j] | ((uint)ll[2*j+1] << 16);
        }
#pragma unroll
        for (int m = 0; m < 10; ++m) {
            chxT_hi[(base + m) * 40 + d_] = hh[m];
            chxT_lo[(base + m) * 40 + d_] = ll[m];
        }
    }
    {   // TT [t][e]
        int t = tid >> 2, c8 = (tid & 3) * 8;
        const float* src = types_h + (size_t)(b * Tq + t) * Hq + n * Dq + c8;
        float4 v0 = *(const float4*)src, v1 = *(const float4*)(src + 4);
        float vv[8] = {v0.x, v0.y, v0.z, v0.w, v1.x, v1.y, v1.z, v1.w};
        uint hp[4], lp[4];
#pragma unroll
        for (int j = 0; j < 4; ++j) {
            uint16_t h0 = f2bf(vv[2*j]), h1 = f2bf(vv[2*j+1]);
            hp[j] = (uint)h0 | ((uint)h1 << 16);
            lp[j] = (uint)f2bf(vv[2*j] - bf2f(h0)) | ((uint)f2bf(vv[2*j+1] - bf2f(h1)) << 16);
        }
        *(uint4*)&TT_hi[t * 40 + c8] = make_uint4(hp[0], hp[1], hp[2], hp[3]);
        *(uint4*)&TT_lo[t * 40 + c8] = make_uint4(lp[0], lp[1], lp[2], lp[3]);
    }
    {   // TTVT [d][t]
        int d_ = tid >> 3, t8 = (tid & 7) * 8;
        const float* src = types_hT + ((size_t)(b * Hq) + n * Dq + d_) * Tq + t8;
        float4 v0 = *(const float4*)src, v1 = *(const float4*)(src + 4);
        float vv[8] = {v0.x, v0.y, v0.z, v0.w, v1.x, v1.y, v1.z, v1.w};
        uint hp[4], lp[4];
#pragma unroll
        for (int j = 0; j < 4; ++j) {
            uint16_t h0 = f2bf(vv[2*j]), h1 = f2bf(vv[2*j+1]);
            hp[j] = (uint)h0 | ((uint)h1 << 16);
            lp[j] = (uint)f2bf(vv[2*j] - bf2f(h0)) | ((uint)f2bf(vv[2*j+1] - bf2f(h1)) << 16);
        }
        *(uint4*)&ttvt_hi[d_ * 72 + t8] = make_uint4(hp[0], hp[1], hp[2], hp[3]);
        *(uint4*)&ttvt_lo[d_ * 72 + t8] = make_uint4(lp[0], lp[1], lp[2], lp[3]);
    }
    if (tid < 80) {
        int gl = l0 + tid;
        int glw = gl >= Lq ? gl - Lq : gl;
        uqe[tid] = uq[(b * NHq + n) * Lq + glw];
        unsigned char mb = mask_b8 ? maskp[b * Lq + glw]
                                   : maskp[(size_t)(b * Lq + glw) * 4];
        maskf[tid] = mb ? 1.f : 0.f;
    } else if (tid >= 96 && tid < 176) {
        int i = tid - 96;
        int gl = l0 - 16 + i;
        int glw = gl < 0 ? gl + Lq : (gl >= Lq ? gl - Lq : gl);
        dsve[i] = dsv[(b * NHq + n) * Lq + glw];
    } else if (tid >= 192) {
        dts[tid - 192] = dt[(b * NHq + n) * Tq + (tid - 192)];
    }
    __syncthreads();    // B1

    // ---------------- P1: cr[l][e] = ctx_h[l] . cross ----------------
    f32x4 cr0 = (f32x4){0.f, 0.f, 0.f, 0.f};
    f32x4 cr1 = (f32x4){0.f, 0.f, 0.f, 0.f};
    {
        short8 axh = *(const short8*)&chxT_hi[(16*g + s) * 40 + 8*Q];
        short8 axl = *(const short8*)&chxT_lo[(16*g + s) * 40 + 8*Q];
        __builtin_amdgcn_s_setprio(1);
        cr0 = __builtin_amdgcn_mfma_f32_16x16x32_bf16(axh, cb0h, cr0, 0, 0, 0);
        cr0 = __builtin_amdgcn_mfma_f32_16x16x32_bf16(axl, cb0h, cr0, 0, 0, 0);
        cr0 = __builtin_amdgcn_mfma_f32_16x16x32_bf16(axh, cb0l, cr0, 0, 0, 0);
        cr1 = __builtin_amdgcn_mfma_f32_16x16x32_bf16(axh, cb1h, cr1, 0, 0, 0);
        cr1 = __builtin_amdgcn_mfma_f32_16x16x32_bf16(axl, cb1h, cr1, 0, 0, 0);
        cr1 = __builtin_amdgcn_mfma_f32_16x16x32_bf16(axh, cb1l, cr1, 0, 0, 0);
        __builtin_amdgcn_s_setprio(0);
    }

    // crle [l][e] bf16 hi/lo (own-wave rows; dedicated region -> no barrier)
#pragma unroll
    for (int r = 0; r < 4; ++r) {
        int row = 16*g + 4*Q + r;
        uint16_t h0 = f2bf(cr0[r]);
        crle_hi[row * 40 + s] = h0;
        crle_lo[row * 40 + s] = f2bf(cr0[r] - bf2f(h0));
        uint16_t h1 = f2bf(cr1[r]);
        crle_hi[row * 40 + 16 + s] = h1;
        crle_lo[row * 40 + 16 + s] = f2bf(cr1[r] - bf2f(h1));
    }

    // ---------------- P2 (t-scores) + P3 (window dots) ----------------
    f32x4 p2[4], p3[2];
#pragma unroll
    for (int c = 0; c < 4; ++c) p2[c] = (f32x4){0.f, 0.f, 0.f, 0.f};
#pragma unroll
    for (int t_ = 0; t_ < 2; ++t_) p3[t_] = (f32x4){0.f, 0.f, 0.f, 0.f};
    {
        short8 cah = *(const short8*)&crle_hi[(16*g + s) * 40 + 8*Q];
        short8 cal = *(const short8*)&crle_lo[(16*g + s) * 40 + 8*Q];
        __builtin_amdgcn_s_setprio(1);
#pragma unroll
        for (int c = 0; c < 4; ++c) {
            short8 bh = *(const short8*)&TT_hi[(s + 16*c) * 40 + 8*Q];
            short8 bl = *(const short8*)&TT_lo[(s + 16*c) * 40 + 8*Q];
            p2[c] = __builtin_amdgcn_mfma_f32_16x16x32_bf16(cah, bh, p2[c], 0, 0, 0);
            p2[c] = __builtin_amdgcn_mfma_f32_16x16x32_bf16(cal, bh, p2[c], 0, 0, 0);
            p2[c] = __builtin_amdgcn_mfma_f32_16x16x32_bf16(cah, bl, p2[c], 0, 0, 0);
        }
#pragma unroll
        for (int t_ = 0; t_ < 2; ++t_) {
            short8 bh = *(const short8*)&chxT_hi[(16*g + 16*t_ + s) * 40 + 8*Q];
            short8 bl = *(const short8*)&chxT_lo[(16*g + 16*t_ + s) * 40 + 8*Q];
            p3[t_] = __builtin_amdgcn_mfma_f32_16x16x32_bf16(cah, bh, p3[t_], 0, 0, 0);
            p3[t_] = __builtin_amdgcn_mfma_f32_16x16x32_bf16(cal, bh, p3[t_], 0, 0, 0);
            p3[t_] = __builtin_amdgcn_mfma_f32_16x16x32_bf16(cah, bl, p3[t_], 0, 0, 0);
        }
        __builtin_amdgcn_s_setprio(0);
    }

    // ---------------- softmax (C-layout: lane = col, 4 rows) ----------------
    float uqr[4], cmr[4], dsr[4], dd[4];
    *(float4*)uqr = *(const float4*)&uqe[16*g + 4*Q];
    *(float4*)cmr = *(const float4*)&maskf[16*g + 4*Q];
    *(float4*)dsr = *(const float4*)&dsve[16*g + 4*Q + 16];
#pragma unroll
    for (int r = 0; r < 4; ++r) dd[r] = dsve[16*g + 4*Q + s + r];
    float dtv[4], uw[2], mw[2];
#pragma unroll
    for (int c = 0; c < 4; ++c) dtv[c] = dts[s + 16*c];
#pragma unroll
    for (int t_ = 0; t_ < 2; ++t_) {
        uw[t_] = uqe[16*g + s + 16*t_];
        mw[t_] = maskf[16*g + s + 16*t_];
    }
    float dsb[4];
#pragma unroll
    for (int r = 0; r < 4; ++r) dsb[r] = __shfl(p3[0][r], 20*Q + r);

    float stt[4][4], rup[2][4], rdn[4], rdn16[4];
#pragma unroll
    for (int c = 0; c < 4; ++c)
#pragma unroll
        for (int r = 0; r < 4; ++r)
            stt[c][r] = leaky(uqr[r] + dtv[c] + p2[c][r]);
#pragma unroll
    for (int t_ = 0; t_ < 2; ++t_)
#pragma unroll
        for (int r = 0; r < 4; ++r) {
            int u = s + 16*t_ - 4*Q - r;
            bool ok = (u >= 1) && (u <= 16) && (l0 + 16*g + s + 16*t_ < Lq)
                      && (mw[t_] > 0.5f);
            rup[t_][r] = ok ? leaky(uw[t_] + dsr[r] + p3[t_][r]) : MASK_FILL;
        }
#pragma unroll
    for (int r = 0; r < 4; ++r) {
        bool okd = (l0 + 16*g + 4*Q + r + s >= 16) && (cmr[r] > 0.5f);
        rdn[r]   = okd ? leaky(uqr[r] + dd[r] + dsb[r]) : MASK_FILL;
        rdn16[r] = (s == 0 && cmr[r] > 0.5f) ? leaky(uqr[r] + dsr[r] + dsb[r])
                                             : MASK_FILL;
    }

    float mx[4];
#pragma unroll
    for (int r = 0; r < 4; ++r) {
        float m = fmaxf(fmaxf(stt[0][r], stt[1][r]), fmaxf(stt[2][r], stt[3][r]));
        m = fmaxf(m, fmaxf(rup[0][r], rup[1][r]));
        m = fmaxf(m, fmaxf(rdn[r], rdn16[r]));
        mx[r] = m;
    }
#pragma unroll
    for (int msk = 1; msk <= 8; msk <<= 1)
#pragma unroll
        for (int r = 0; r < 4; ++r) mx[r] = fmaxf(mx[r], __shfl_xor(mx[r], msk));

    float sTU[4] = {0.f, 0.f, 0.f, 0.f}, sD[4];
#pragma unroll
    for (int c = 0; c < 4; ++c)
#pragma unroll
        for (int r = 0; r < 4; ++r) {
            stt[c][r] = __expf(stt[c][r] - mx[r]);
            sTU[r] += stt[c][r];
        }
#pragma unroll
    for (int t_ = 0; t_ < 2; ++t_)
#pragma unroll
        for (int r = 0; r < 4; ++r) {
            rup[t_][r] = __expf(rup[t_][r] - mx[r]);
            sTU[r] += rup[t_][r];
        }
#pragma unroll
    for (int r = 0; r < 4; ++r) {
        rdn[r] = __expf(rdn[r] - mx[r]);
        rdn16[r] = __expf(rdn16[r] - mx[r]);
        sD[r] = rdn[r] + rdn16[r];
    }
#pragma unroll
    for (int msk = 1; msk <= 8; msk <<= 1)
#pragma unroll
        for (int r = 0; r < 4; ++r) {
            sTU[r] += __shfl_xor(sTU[r], msk);
            sD[r]  += __shfl_xor(sD[r], msk);
        }
    float inv[4], wself[4];
#pragma unroll
    for (int r = 0; r < 4; ++r) {
        inv[r] = 1.f / (sTU[r] + sD[r]);
        wself[r] = sD[r] * inv[r];
    }

    __syncthreads();    // B4: all TT/chxT reads done; alias as waT/waw

    // ---------------- weight writes (bf16 hi/lo) ----------------
#pragma unroll
    for (int r = 0; r < 4; ++r) {
        int row = 16*g + 4*Q + r;
#pragma unroll
        for (int c = 0; c < 4; ++c) {
            float v = stt[c][r] * inv[r];
            uint16_t h = f2bf(v);
            waT_hi[row * 72 + s + 16*c] = h;
            waT_lo[row * 72 + s + 16*c] = f2bf(v - bf2f(h));
        }
#pragma unroll
        for (int t_ = 0; t_ < 2; ++t_) {
            int u = s + 16*t_ - 4*Q - r;
            float v = (u == 0) ? wself[r]
                    : ((u >= 1 && u <= 16) ? rup[t_][r] * inv[r] : 0.f);
            uint16_t h = f2bf(v);
            waw_hi[row * 40 + s + 16*t_] = h;
            waw_lo[row * 40 + s + 16*t_] = f2bf(v - bf2f(h));
        }
    }
    // (no barrier: epilogue reads only rows this wave wrote)

    // early ctx load for the +context add ([l][d] orientation, coalesced)
    int rowl = lane & 15, p = lane >> 4;
    int lcol = l0 + 16*g + rowl;
    float4 cx0, cx1;
    {
        const float4* cp = (const float4*)(ctx + (size_t)(b * Lq + lcol) * Hq
                                           + n * Dq + 8*p);
        cx0 = cp[0]; cx1 = cp[1];
    }

    // ---------------- epilogue MFMAs: updT[d][l] ----------------
    f32x4 a0 = (f32x4){0.f, 0.f, 0.f, 0.f};
    f32x4 a1 = (f32x4){0.f, 0.f, 0.f, 0.f};
    __builtin_amdgcn_s_setprio(1);
#pragma unroll
    for (int ks = 0; ks < 2; ++ks) {
        short8 bh = *(const short8*)&waT_hi[(16*g + s) * 72 + 32*ks + 8*Q];
        short8 bl = *(const short8*)&waT_lo[(16*g + s) * 72 + 32*ks + 8*Q];
        short8 t0h = *(const short8*)&ttvt_hi[s * 72 + 32*ks + 8*Q];
        short8 t0l = *(const short8*)&ttvt_lo[s * 72 + 32*ks + 8*Q];
        short8 t1h = *(const short8*)&ttvt_hi[(16 + s) * 72 + 32*ks + 8*Q];
        short8 t1l = *(const short8*)&ttvt_lo[(16 + s) * 72 + 32*ks + 8*Q];
        a0 = __builtin_amdgcn_mfma_f32_16x16x32_bf16(t0h, bh, a0, 0, 0, 0);
        a0 = __builtin_amdgcn_mfma_f32_16x16x32_bf16(t0l, bh, a0, 0, 0, 0);
        a0 = __builtin_amdgcn_mfma_f32_16x16x32_bf16(t0h, bl, a0, 0, 0, 0);
        a1 = __builtin_amdgcn_mfma_f32_16x16x32_bf16(t1h, bh, a1, 0, 0, 0);
        a1 = __builtin_amdgcn_mfma_f32_16x16x32_bf16(t1l, bh, a1, 0, 0, 0);
        a1 = __builtin_amdgcn_mfma_f32_16x16x32_bf16(t1h, bl, a1, 0, 0, 0);
    }
    {
        short8 wbh = *(const short8*)&waw_hi[(16*g + s) * 40 + 8*Q];
        short8 wbl = *(const short8*)&waw_lo[(16*g + s) * 40 + 8*Q];
        short8 c0h = *(const short8*)&chvt_hi[s * 80 + 16*g + 8*Q];
        short8 c0l = *(const short8*)&chvt_lo[s * 80 + 16*g + 8*Q];
        short8 c1h = *(const short8*)&chvt_hi[(16 + s) * 80 + 16*g + 8*Q];
        short8 c1l = *(const short8*)&chvt_lo[(16 + s) * 80 + 16*g + 8*Q];
        a0 = __builtin_amdgcn_mfma_f32_16x16x32_bf16(c0h, wbh, a0, 0, 0, 0);
        a0 = __builtin_amdgcn_mfma_f32_16x16x32_bf16(c0l, wbh, a0, 0, 0, 0);
        a0 = __builtin_amdgcn_mfma_f32_16x16x32_bf16(c0h, wbl, a0, 0, 0, 0);
        a1 = __builtin_amdgcn_mfma_f32_16x16x32_bf16(c1h, wbh, a1, 0, 0, 0);
        a1 = __builtin_amdgcn_mfma_f32_16x16x32_bf16(c1l, wbh, a1, 0, 0, 0);
        a1 = __builtin_amdgcn_mfma_f32_16x16x32_bf16(c1h, wbl, a1, 0, 0, 0);
    }
    __builtin_amdgcn_s_setprio(0);

    // ---------- C write: in-wave LDS transpose -> coalesced stores ----------
    {
        float* cst = (float*)(smem + 2304 * g);
        *(float4*)&cst[s * 32 + ((4*Q + 4*s) & 31)]
            = make_float4(a0[0], a0[1], a0[2], a0[3]);
        *(float4*)&cst[s * 32 + ((16 + 4*Q + 4*s) & 31)]
            = make_float4(a1[0], a1[1], a1[2], a1[3]);
        float4 u0 = *(float4*)&cst[rowl * 32 + ((8*p + 4*rowl) & 31)];
        float4 u1 = *(float4*)&cst[rowl * 32 + ((8*p + 4 + 4*rowl) & 31)];
        float vv[8] = {u0.x + cx0.x, u0.y + cx0.y, u0.z + cx0.z, u0.w + cx0.w,
                       u1.x + cx1.x, u1.y + cx1.y, u1.z + cx1.z, u1.w + cx1.w};
        uint hu[4], lu[4];
#pragma unroll
        for (int j = 0; j < 4; ++j) {
            uint16_t h0 = f2bf(vv[2*j]), h1 = f2bf(vv[2*j+1]);
            hu[j] = (uint)h0 | ((uint)h1 << 16);
            lu[j] = (uint)f2bf(vv[2*j] - bf2f(h0))
                  | ((uint)f2bf(vv[2*j+1] - bf2f(h1)) << 16);
        }
        size_t obase = (size_t)(b * Lq + lcol) * Hq + n * Dq + 8*p;
        *(uint4*)(updp_hi + obase) = make_uint4(hu[0], hu[1], hu[2], hu[3]);
        *(uint4*)(updp_lo + obase) = make_uint4(lu[0], lu[1], lu[2], lu[3]);
    }
}

// ------ output GEMM via MFMA + tanh (LDS-staged packed A, coalesced) --------
__global__ void __launch_bounds__(256) k_out(
        const uint16_t* __restrict__ up_hi, const uint16_t* __restrict__ up_lo,
        const uint16_t* __restrict__ wp_hi, const uint16_t* __restrict__ wp_lo,
        const float* __restrict__ bo, float* __restrict__ out) {
    int row0 = blockIdx.x * MB;
    int tid = threadIdx.x;
    int w = tid >> 6, l = tid & 63;
    __shared__ __align__(16) uint16_t a_hi[MB * APAD];
    __shared__ __align__(16) uint16_t a_lo[MB * APAD];

    {   // coalesced copy of pre-packed A: 16 rows x 256 cols x 2 buffers
        const uint4* sh = (const uint4*)(up_hi + (size_t)row0 * Hq);
        const uint4* sl = (const uint4*)(up_lo + (size_t)row0 * Hq);
#pragma unroll
        for (int j = 0; j < 2; ++j) {
            int f = tid + j * 256;
            int r = f >> 5, c8 = (f & 31) * 8;
            *(uint4*)&a_hi[r * APAD + c8] = sh[f];
            *(uint4*)&a_lo[r * APAD + c8] = sl[f];
        }
    }
    __syncthreads();

    int nt0 = w * 4;
    int m = l & 15, quad = l >> 4;
    f32x4 acc[4];
#pragma unroll
    for (int t = 0; t < 4; ++t) acc[t] = (f32x4){0.f, 0.f, 0.f, 0.f};
#pragma unroll
    for (int kc = 0; kc < 8; ++kc) {
        short8 ah = *(const short8*)&a_hi[m * APAD + kc * 32 + quad * 8];
        short8 al = *(const short8*)&a_lo[m * APAD + kc * 32 + quad * 8];
#pragma unroll
        for (int t = 0; t < 4; ++t) {
            int fragi = (nt0 + t) * 8 + kc;
            short8 wh = *(const short8*)&wp_hi[fragi * 512 + l * 8];
            short8 wl = *(const short8*)&wp_lo[fragi * 512 + l * 8];
            acc[t] = __builtin_amdgcn_mfma_f32_16x16x32_bf16(ah, wh, acc[t], 0, 0, 0);
            acc[t] = __builtin_amdgcn_mfma_f32_16x16x32_bf16(ah, wl, acc[t], 0, 0, 0);
            acc[t] = __builtin_amdgcn_mfma_f32_16x16x32_bf16(al, wh, acc[t], 0, 0, 0);
        }
    }
#pragma unroll
    for (int t = 0; t < 4; ++t) {
        int col = (nt0 + t) * 16 + m;
        float bv = bo[col];
#pragma unroll
        for (int r = 0; r < 4; ++r)
            out[(size_t)(row0 + quad * 4 + r) * Hq + col] = tanhf(acc[t][r] + bv);
    }
}

extern "C" void kernel_launch(void* const* d_in, const int* in_sizes, int n_in,
                              void* d_out, int out_size, void* d_ws, size_t ws_size,
                              hipStream_t stream) {
    const float* context   = (const float*)d_in[0];
    const float* types     = (const float*)d_in[1];
    const unsigned char* cmask = (const unsigned char*)d_in[2];
    const float* W_types   = (const float*)d_in[3];
    const float* b_types   = (const float*)d_in[4];
    const float* W_context = (const float*)d_in[5];
    const float* b_context = (const float*)d_in[6];
    const float* upon      = (const float*)d_in[7];
    const float* down      = (const float*)d_in[8];
    const float* cross     = (const float*)d_in[9];
    const float* W_out     = (const float*)d_in[10];
    const float* b_out     = (const float*)d_in[11];
    float* out = (float*)d_out;
    float* ws  = (float*)d_ws;

    float* ctx_hT     = ws;                            // [b][n][d][l] 16 MB
    uint16_t* updp_hi = (uint16_t*)(ws + 4194304);     // 8 MB packed hi
    uint16_t* updp_lo = updp_hi + 4194304;             // 8 MB packed lo
    uint16_t* wcp_hi  = (uint16_t*)(ws + 8388608);
    uint16_t* wcp_lo  = wcp_hi + 65536;
    uint16_t* wop_hi  = wcp_hi + 131072;
    uint16_t* wop_lo  = wcp_hi + 196608;

    // R16: small intermediates moved from d_out scratch to ws (+48 MB)
    float* types_h  = ws + 12582912;        // 65536   [b][t][h]
    float* types_hT = types_h + 65536;      // 65536   [b][n][d][t]
    float* down_t   = types_hT + 65536;     // 2048
    float* uqp      = down_t + 2048;        // 131072
    float* dsvp     = uqp + 131072;         // 131072

    k_prep<<<128 + Bq * Tq, 256, 0, stream>>>(W_context, W_out,
                                              wcp_hi, wcp_lo, wop_hi, wop_lo,
                                              types, W_types, b_types, down,
                                              types_h, types_hT, down_t);
    k_ctx<<<Bq * Lq / MB, 256, 0, stream>>>(context, wcp_hi, wcp_lo, b_context,
                                            upon, down, ctx_hT, uqp, dsvp);
    k_attn<<<Bq * NHq * (Lq / TLq), 256, 0, stream>>>(ctx_hT, types_h, types_hT, cross,
                                                      uqp, dsvp, down_t, cmask,
                                                      context, updp_hi, updp_lo);
    k_out<<<Bq * Lq / MB, 256, 0, stream>>>(updp_hi, updp_lo, wop_hi, wop_lo,
                                            b_out, out);
}